// Round 8
// baseline (344.542 us; speedup 1.0000x reference)
//
#include <hip/hip_runtime.h>
#include <hip/hip_bf16.h>
#include <math.h>

#define NPTS 4096
#define DINF 26
#define LOG2E 1.44269504088896f

typedef float f32x4v __attribute__((ext_vector_type(4)));
typedef __bf16 bf16x8v __attribute__((ext_vector_type(8)));

__device__ __forceinline__ float ldb(const float* p, int i){ return p[i]; }
__device__ __forceinline__ float lk(float v){ return v >= 0.0f ? v : 0.2f*v; }
__device__ __forceinline__ float wsum64(float v){
#pragma unroll
  for(int o=32;o>0;o>>=1) v += __shfl_down(v,o);
  return v;
}
__device__ __forceinline__ unsigned short f2bf(float f){
  return __builtin_bit_cast(unsigned short, __float2bfloat16(f));
}
__device__ __forceinline__ float bf2f(unsigned short u){
  return __bfloat162float(__builtin_bit_cast(__hip_bfloat16, u));
}
__device__ __forceinline__ unsigned pk2(float a, float b){
  return (unsigned)f2bf(a) | ((unsigned)f2bf(b)<<16);
}
// hi/lo split: col = hi + lo recovers ~16 mantissa bits through 2 MFMAs.
__device__ __forceinline__ void split2(float a, float b, unsigned& h, unsigned& l){
  unsigned short ah=f2bf(a), bh=f2bf(b);
  float ar = a - bf2f(ah), br = b - bf2f(bh);
  h = (unsigned)ah | ((unsigned)bh<<16);
  l = (unsigned)f2bf(ar) | ((unsigned)f2bf(br)<<16);
}
// intra-wave LDS write->read ordering (DS pipe in-order per wave; stops
// compiler pipelining across the exchange — R3/R4 lesson).
__device__ __forceinline__ void wave_lds_fence(){
  __builtin_amdgcn_wave_barrier();
  __builtin_amdgcn_s_waitcnt(0xC07F);   // lgkmcnt(0)
  __builtin_amdgcn_wave_barrier();
}
__device__ __forceinline__ void tangent(float nx,float ny,float nz,float* t1,float* t2){
  float s = (nz >= 0.0f) ? 1.0f : -1.0f;
  float a = -1.0f/(s+nz);
  float b = nx*ny*a;
  t1[0]=1.0f+s*nx*nx*a; t1[1]=s*b; t1[2]=-s*nx;
  t2[0]=b; t2[1]=s+ny*ny*a; t2[2]=-ny;
}

// ---- k0 ----
__global__ __launch_bounds__(256) void k0_convert(const float* __restrict__ verts,
                                                  const float* __restrict__ vnorm,
                                                  const float* __restrict__ x,
                                                  float* __restrict__ vertsF,
                                                  float* __restrict__ nF,
                                                  float* __restrict__ pF,
                                                  float* __restrict__ xfF){
  int i = blockIdx.x*blockDim.x + threadIdx.x;
  if(i >= NPTS) return;
#pragma unroll
  for(int d=0;d<3;d++){
    float v = verts[i*3+d];
    vertsF[i*3+d]=v;
    pF[i*3+d]=v*(1.0f/9.0f);
    nF[i*3+d]=vnorm[i*3+d];
  }
#pragma unroll
  for(int c=0;c<16;c++) xfF[i*DINF+c]=x[i*16+c];
}

// ---- k1m: curvature pass 1 via MFMA + hi/lo split; j-split x2, atomics ----
// Block: 16-i tile, half the j range (8 waves x 256 j). Partial moments
// atomicAdd into zeroed sc. sc per scale: s0, sx, sxx6, RAW un.
__global__ __launch_bounds__(512) void k1m(const float* __restrict__ vertsF,
                                           const float* __restrict__ nF,
                                           float* __restrict__ sc){
  __shared__ unsigned short fbh[8][64][18];
  __shared__ unsigned short fbl[8][64][18];
  __shared__ float vq[8][64][4];
  __shared__ float red[8][16][16];
  const float c2e[5] = {0.5f*LOG2E, 0.125f*LOG2E, (1.0f/18.0f)*LOG2E,
                        0.02f*LOG2E, 0.005f*LOG2E};
  int lane = threadIdx.x & 63, w = threadIdx.x >> 6;
  int c16 = lane & 15, q = lane >> 4;
  int it = blockIdx.x >> 1, jh = blockIdx.x & 1;
  int i0 = it*16;
  int ia = i0 + c16;
  float vix=vertsF[ia*3+0], viy=vertsF[ia*3+1], viz=vertsF[ia*3+2];
  float nsqi = vix*vix+viy*viy+viz*viz;
  f32x4v acc[5];
#pragma unroll
  for(int s=0;s<5;s++) acc[s] = (f32x4v){0.0f,0.0f,0.0f,0.0f};

  int jbeg = jh*2048 + w*256;
#pragma unroll 1
  for(int jb = jbeg; jb < jbeg+256; jb += 64){
    int j = jb + lane;
    float vx=vertsF[j*3+0], vy=vertsF[j*3+1], vz=vertsF[j*3+2];
    float nx=nF[j*3+0], ny=nF[j*3+1], nz=nF[j*3+2];
    float nsq = vx*vx+vy*vy+vz*vz;
    unsigned* fh = (unsigned*)&fbh[w][lane][0];
    unsigned* fl = (unsigned*)&fbl[w][lane][0];
    unsigned h,l;
    split2(1.0f, vx, h,l);      fh[0]=h; fl[0]=l;
    split2(vy, vz, h,l);        fh[1]=h; fl[1]=l;
    split2(vx*vx, vx*vy, h,l);  fh[2]=h; fl[2]=l;
    split2(vx*vz, vy*vy, h,l);  fh[3]=h; fl[3]=l;
    split2(vy*vz, vz*vz, h,l);  fh[4]=h; fl[4]=l;
    split2(nx, ny, h,l);        fh[5]=h; fl[5]=l;
    split2(nz, 0.0f, h,l);      fh[6]=h; fl[6]=l;
    fh[7]=0u; fl[7]=0u; fh[8]=0u; fl[8]=0u;
    *(float4*)&vq[w][lane][0] = make_float4(vx,vy,vz,nsq);
    wave_lds_fence();
#pragma unroll
    for(int q2=0;q2<2;q2++){
      int rb = q2*32 + q*8;
      bf16x8v bh, bl;
#pragma unroll
      for(int t=0;t<8;t++){
        bh[t] = __builtin_bit_cast(__bf16, fbh[w][rb+t][c16]);
        bl[t] = __builtin_bit_cast(__bf16, fbl[w][rb+t][c16]);
      }
      bf16x8v af[5];
#pragma unroll
      for(int t=0;t<8;t++){
        float4 vv = *(const float4*)&vq[w][rb+t][0];
        float dot = vix*vv.x + viy*vv.y + viz*vv.z;
        float d2 = fmaxf(nsqi + vv.w - 2.0f*dot, 0.0f);
#pragma unroll
        for(int s=0;s<5;s++)
          af[s][t] = __builtin_bit_cast(__bf16, f2bf(exp2f(-d2*c2e[s])));
      }
#pragma unroll
      for(int s=0;s<5;s++){
        acc[s] = __builtin_amdgcn_mfma_f32_16x16x32_bf16(af[s], bh, acc[s], 0,0,0);
        acc[s] = __builtin_amdgcn_mfma_f32_16x16x32_bf16(af[s], bl, acc[s], 0,0,0);
      }
    }
    wave_lds_fence();
  }
  // 8-wave reduce, atomic-accumulate moments
#pragma unroll
  for(int s=0;s<5;s++){
#pragma unroll
    for(int r=0;r<4;r++) red[w][q*4+r][c16] = acc[s][r];
    __syncthreads();
    if(w==0){
      float* base = sc + (size_t)s*13*NPTS;
#pragma unroll
      for(int r=0;r<4;r++){
        int m = q*4+r, i = i0+m;
        float D = 0.0f;
#pragma unroll
        for(int ww=0;ww<8;ww++) D += red[ww][m][c16];
        if(c16==0)       atomicAdd(&base[i], D);
        else if(c16<4)   atomicAdd(&base[NPTS + i*3 + (c16-1)], D);
        else if(c16<10)  atomicAdd(&base[4*NPTS + i*6 + (c16-4)], D);
        else if(c16<13)  atomicAdd(&base[10*NPTS + i*3 + (c16-10)], D);
      }
    }
    __syncthreads();
  }
}

// ---- k2m: curvature pass 2 moments via MFMA; j-split x2, atomics ----------
// mom2[(s*N+i)*12 + c] = sum_j w_s(i,j)*F2_s[j][c], F2_s=[ns(3), v⊗ns(9)]
__global__ __launch_bounds__(512) void k2m(const float* __restrict__ vertsF,
                                           const float* __restrict__ sc,
                                           float* __restrict__ mom2){
  __shared__ unsigned short fbh[8][64][18];
  __shared__ unsigned short fbl[8][64][18];
  __shared__ float vq[8][64][4];
  __shared__ float red[8][16][16];
  const float c2e[5] = {0.5f*LOG2E, 0.125f*LOG2E, (1.0f/18.0f)*LOG2E,
                        0.02f*LOG2E, 0.005f*LOG2E};
  int lane = threadIdx.x & 63, w = threadIdx.x >> 6;
  int c16 = lane & 15, q = lane >> 4;
  int it = blockIdx.x >> 1, jh = blockIdx.x & 1;
  int i0 = it*16;
  int ia = i0 + c16;
  float vix=vertsF[ia*3+0], viy=vertsF[ia*3+1], viz=vertsF[ia*3+2];
  float nsqi = vix*vix+viy*viy+viz*viz;
  f32x4v acc[5];
#pragma unroll
  for(int s=0;s<5;s++) acc[s] = (f32x4v){0.0f,0.0f,0.0f,0.0f};

  int jbeg = jh*2048 + w*256;
#pragma unroll 1
  for(int jb = jbeg; jb < jbeg+256; jb += 64){
    int j = jb + lane;
    float vx=vertsF[j*3+0], vy=vertsF[j*3+1], vz=vertsF[j*3+2];
    float nsq = vx*vx+vy*vy+vz*vz;
    *(float4*)&vq[w][lane][0] = make_float4(vx,vy,vz,nsq);
    wave_lds_fence();
    float d2c[2][8];
#pragma unroll
    for(int q2=0;q2<2;q2++)
#pragma unroll
      for(int t=0;t<8;t++){
        float4 vv = *(const float4*)&vq[w][q2*32+q*8+t][0];
        float dot = vix*vv.x + viy*vv.y + viz*vv.z;
        d2c[q2][t] = fmaxf(nsqi + vv.w - 2.0f*dot, 0.0f);
      }
#pragma unroll
    for(int s=0;s<5;s++){
      const float* ub = sc + (size_t)s*13*NPTS + 10*NPTS + (size_t)j*3;
      float ux=ub[0], uy=ub[1], uz=ub[2];
      float inv = 1.0f/fmaxf(sqrtf(ux*ux+uy*uy+uz*uz), 1e-12f);
      float n0=ux*inv, n1=uy*inv, n2=uz*inv;
      unsigned* fh = (unsigned*)&fbh[w][lane][0];
      unsigned* fl = (unsigned*)&fbl[w][lane][0];
      unsigned h,l;
      split2(n0, n1, h,l);        fh[0]=h; fl[0]=l;
      split2(n2, vx*n0, h,l);     fh[1]=h; fl[1]=l;
      split2(vx*n1, vx*n2, h,l);  fh[2]=h; fl[2]=l;
      split2(vy*n0, vy*n1, h,l);  fh[3]=h; fl[3]=l;
      split2(vy*n2, vz*n0, h,l);  fh[4]=h; fl[4]=l;
      split2(vz*n1, vz*n2, h,l);  fh[5]=h; fl[5]=l;
      fh[6]=0u; fl[6]=0u; fh[7]=0u; fl[7]=0u; fh[8]=0u; fl[8]=0u;
      wave_lds_fence();
#pragma unroll
      for(int q2=0;q2<2;q2++){
        int rb = q2*32 + q*8;
        bf16x8v af, bh, bl;
#pragma unroll
        for(int t=0;t<8;t++){
          af[t] = __builtin_bit_cast(__bf16, f2bf(exp2f(-d2c[q2][t]*c2e[s])));
          bh[t] = __builtin_bit_cast(__bf16, fbh[w][rb+t][c16]);
          bl[t] = __builtin_bit_cast(__bf16, fbl[w][rb+t][c16]);
        }
        acc[s] = __builtin_amdgcn_mfma_f32_16x16x32_bf16(af, bh, acc[s], 0,0,0);
        acc[s] = __builtin_amdgcn_mfma_f32_16x16x32_bf16(af, bl, acc[s], 0,0,0);
      }
      wave_lds_fence();
    }
  }
#pragma unroll
  for(int s=0;s<5;s++){
#pragma unroll
    for(int r=0;r<4;r++) red[w][q*4+r][c16] = acc[s][r];
    __syncthreads();
    if(w==0){
#pragma unroll
      for(int r=0;r<4;r++){
        int m = q*4+r, i = i0+m;
        float D = 0.0f;
#pragma unroll
        for(int ww=0;ww<8;ww++) D += red[ww][m][c16];
        if(c16<12) atomicAdd(&mom2[((size_t)s*NPTS + i)*12 + c16], D);
      }
    }
    __syncthreads();
  }
}

// ---- k2s: per-(i,scale) curvature solve ------------------------------------
__global__ __launch_bounds__(256) void k2s(const float* __restrict__ vertsF,
                                           const float* __restrict__ sc,
                                           const float* __restrict__ mom2,
                                           float* __restrict__ xfF){
  int idx = blockIdx.x*256 + threadIdx.x;      // 20480 = 5*4096
  int i = idx & (NPTS-1);
  int s = idx >> 12;
  const float* base = sc + (size_t)s*13*NPTS;
  float v[3] = { vertsF[i*3+0], vertsF[i*3+1], vertsF[i*3+2] };
  float s0 = base[i];
  float sx[3] = { base[NPTS+i*3+0], base[NPTS+i*3+1], base[NPTS+i*3+2] };
  float sxx6[6];
#pragma unroll
  for(int k=0;k<6;k++) sxx6[k]=base[4*NPTS+i*6+k];
  float ux=base[10*NPTS+i*3+0], uy=base[10*NPTS+i*3+1], uz=base[10*NPTS+i*3+2];
  float invn = 1.0f/fmaxf(sqrtf(ux*ux+uy*uy+uz*uz), 1e-12f);
  float nsi[3] = { ux*invn, uy*invn, uz*invn };
  const float* M2 = mom2 + ((size_t)s*NPTS + i)*12;
  float sn[3] = { M2[0], M2[1], M2[2] };
  float sxn[3][3];
#pragma unroll
  for(int a=0;a<3;a++)
#pragma unroll
    for(int b=0;b<3;b++) sxn[a][b]=M2[3+a*3+b];
  const int m6[3][3]={{0,1,2},{1,3,4},{2,4,5}};
  float cxx[3][3], cxn[3][3];
#pragma unroll
  for(int a=0;a<3;a++)
#pragma unroll
    for(int b=0;b<3;b++){
      cxx[a][b]=sxx6[m6[a][b]] - v[a]*sx[b] - sx[a]*v[b] + s0*v[a]*v[b];
      cxn[a][b]=sxn[a][b]    - v[a]*sn[b] - sx[a]*nsi[b] + s0*v[a]*nsi[b];
    }
  float t1[3],t2[3];
  tangent(nsi[0],nsi[1],nsi[2],t1,t2);
  float ppt[2][2], pqt[2][2];
#pragma unroll
  for(int k=0;k<2;k++){
    const float* tk = (k==0)?t1:t2;
#pragma unroll
    for(int l=0;l<2;l++){
      const float* tl = (l==0)?t1:t2;
      float accx=0.0f, accn=0.0f;
#pragma unroll
      for(int a=0;a<3;a++)
#pragma unroll
        for(int b=0;b<3;b++){
          accx += tk[a]*cxx[a][b]*tl[b];
          accn += tk[a]*cxn[a][b]*tl[b];
        }
      ppt[k][l]=accx + ((k==l)?0.01f:0.0f);
      pqt[k][l]=accn;
    }
  }
  float det = ppt[0][0]*ppt[1][1]-ppt[0][1]*ppt[1][0];
  float id = 1.0f/det;
  float S00=( ppt[1][1]*pqt[0][0]-ppt[0][1]*pqt[1][0])*id;
  float S01=( ppt[1][1]*pqt[0][1]-ppt[0][1]*pqt[1][1])*id;
  float S10=(-ppt[1][0]*pqt[0][0]+ppt[0][0]*pqt[1][0])*id;
  float S11=(-ppt[1][0]*pqt[0][1]+ppt[0][0]*pqt[1][1])*id;
  float f0=fminf(fmaxf(S00+S11,-1.0f),1.0f);
  float f1=fminf(fmaxf(S00*S11-S01*S10,-1.0f),1.0f);
  xfF[i*DINF+16+2*s]=f0;
  xfF[i*DINF+17+2*s]=f1;
}

// ---- k3 ----
__global__ __launch_bounds__(256) void k3_mlps(const float* __restrict__ xfF,
    const float* os_w1, const float* os_b1, const float* os_w2, const float* os_b2,
    const float* ni_w1, const float* ni_b1, const float* ni_w2, const float* ni_b2,
    float* __restrict__ wOS, float* __restrict__ hPre, float* __restrict__ stats){
  int i = blockIdx.x*256 + threadIdx.x;
  int lane = threadIdx.x & 63;
  float xf[DINF];
#pragma unroll
  for(int k=0;k<DINF;k++) xf[k]=xfF[i*DINF+k];
  float h1[16];
#pragma unroll
  for(int o=0;o<16;o++){
    float t=ldb(os_b1,o);
#pragma unroll
    for(int k=0;k<DINF;k++) t += xf[k]*ldb(os_w1,o*DINF+k);
    h1[o]=lk(t);
  }
  float w=ldb(os_b2,0);
#pragma unroll
  for(int o=0;o<16;o++) w += h1[o]*ldb(os_w2,o);
  wOS[i]=w;
#pragma unroll
  for(int o=0;o<16;o++){
    float t=ldb(ni_b1,o);
#pragma unroll
    for(int k=0;k<DINF;k++) t += xf[k]*ldb(ni_w1,o*DINF+k);
    h1[o]=lk(t);
  }
  float h2[16];
#pragma unroll
  for(int o=0;o<16;o++){
    float t=ldb(ni_b2,o);
#pragma unroll
    for(int k=0;k<16;k++) t += h1[k]*ldb(ni_w2,o*16+k);
    h2[o]=lk(t);
    hPre[i*16+o]=h2[o];
  }
  float gs[4]={0,0,0,0}, gq[4]={0,0,0,0};
#pragma unroll
  for(int c=0;c<16;c++){ gs[c>>2]+=h2[c]; gq[c>>2]+=h2[c]*h2[c]; }
  __shared__ float ls[8];
  if(threadIdx.x<8) ls[threadIdx.x]=0.0f;
  __syncthreads();
#pragma unroll
  for(int g=0;g<4;g++){ gs[g]=wsum64(gs[g]); gq[g]=wsum64(gq[g]); }
  if(lane==0){
#pragma unroll
    for(int g=0;g<4;g++){ atomicAdd(&ls[2*g],gs[g]); atomicAdd(&ls[2*g+1],gq[g]); }
  }
  __syncthreads();
  if(threadIdx.x<8) atomicAdd(&stats[threadIdx.x], ls[threadIdx.x]);
}

// ---- k3c: GN -> bf16 transposed hTb[16][4096] ----
__global__ __launch_bounds__(256) void k3c_gn(const float* __restrict__ hPre,
                                              const float* __restrict__ stats,
                                              const float* gw, const float* gb,
                                              unsigned short* __restrict__ hTb){
  int i = blockIdx.x*256 + threadIdx.x;
  float m[4], r[4];
#pragma unroll
  for(int g=0;g<4;g++){
    float mean = stats[2*g]*(1.0f/(4.0f*NPTS));
    float var  = stats[2*g+1]*(1.0f/(4.0f*NPTS)) - mean*mean;
    m[g]=mean; r[g]=1.0f/sqrtf(var+1e-5f);
  }
#pragma unroll
  for(int c=0;c<16;c++){
    int g=c>>2;
    float v=(hPre[i*16+c]-m[g])*r[g]*ldb(gw,c)+ldb(gb,c);
    hTb[c*NPTS+i]=f2bf(v);
  }
}

// ---- k4: 2-way j split per i -----------------------------------------------
__global__ __launch_bounds__(256) void k4_ov(const float* __restrict__ pF,
                                             const float* __restrict__ nF,
                                             const float* __restrict__ wOS,
                                             float* __restrict__ nuvF){
  __shared__ float part[4][4];
  int lane = threadIdx.x & 63;
  int w = threadIdx.x >> 6;
  int ii = w >> 1, jh = w & 1;
  int i = blockIdx.x*2 + ii;
  float pix=pF[i*3+0], piy=pF[i*3+1], piz=pF[i*3+2];
  float nix=nF[i*3+0], niy=nF[i*3+1], niz=nF[i*3+2];
  float a0=0,a1=0,a2=0,a3=0;
#pragma unroll 1
  for(int j=jh*2048+lane; j<jh*2048+2048; j+=64){
    float px=pF[j*3+0], py=pF[j*3+1], pz=pF[j*3+2];
    float nx=nF[j*3+0], ny=nF[j*3+1], nz=nF[j*3+2];
    float wj=wOS[j];
    float dx=px-pix, dy=py-piy, dz=pz-piz;
    float d2=dx*dx+dy*dy+dz*dz;
    float f=2.0f-(nx*nix+ny*niy+nz*niz);
    float Wv=__expf(-d2*f*f);
    float Ww=Wv*wj;
    a0+=Ww*px; a1+=Ww*py; a2+=Ww*pz; a3+=Ww;
  }
  a0=wsum64(a0); a1=wsum64(a1); a2=wsum64(a2); a3=wsum64(a3);
  if(lane==0){ part[w][0]=a0; part[w][1]=a1; part[w][2]=a2; part[w][3]=a3; }
  __syncthreads();
  if(lane==0 && jh==0){
    a0=part[w][0]+part[w+1][0]; a1=part[w][1]+part[w+1][1];
    a2=part[w][2]+part[w+1][2]; a3=part[w][3]+part[w+1][3];
    float o0=a0-a3*pix, o1=a1-a3*piy, o2=a2-a3*piz;
    float t1[3],t2[3];
    tangent(nix,niy,niz,t1,t2);
    float ov0=t1[0]*o0+t1[1]*o1+t1[2]*o2+1e-5f;
    float ov1=t2[0]*o0+t2[1]*o1+t2[2]*o2+1e-5f;
    float inv=1.0f/sqrtf(ov0*ov0+ov1*ov1);
    float ex=ov0*inv, ey=ov1*inv;
    nuvF[i*9+0]=nix; nuvF[i*9+1]=niy; nuvF[i*9+2]=niz;
    nuvF[i*9+3]= ex*t1[0]+ey*t2[0]; nuvF[i*9+4]= ex*t1[1]+ey*t2[1]; nuvF[i*9+5]= ex*t1[2]+ey*t2[2];
    nuvF[i*9+6]=-ey*t1[0]+ex*t2[0]; nuvF[i*9+7]=-ey*t1[1]+ex*t2[1]; nuvF[i*9+8]=-ey*t1[2]+ex*t2[2];
  }
}

// ---- k5: conv via MFMA; 2 waves per i (j halves), 2 i per block ------------
__global__ __launch_bounds__(256) void k5_conv(const float* __restrict__ pF,
                                               const float* __restrict__ nF,
                                               const float* __restrict__ nuvF,
                                               const unsigned short* __restrict__ hTb,
                                               const float* cv_a1, const float* cv_b1,
                                               const float* cv_a2, const float* cv_b2,
                                               float* __restrict__ xiF){
  __shared__ unsigned short zs[4][64][18];
  __shared__ float red[4][64][4];
  int lane = threadIdx.x & 63;
  int w = threadIdx.x >> 6;
  int ii = w >> 1, jh = w & 1;
  int i = blockIdx.x*2 + ii;
  int c16 = lane & 15, q = lane >> 4;
  unsigned* zr = (unsigned*)&zs[w][lane][0];
#pragma unroll
  for(int c=0;c<9;c++) zr[c]=0u;

  float pix=pF[i*3+0], piy=pF[i*3+1], piz=pF[i*3+2];
  float nu[9];
#pragma unroll
  for(int k=0;k<9;k++) nu[k]=nuvF[i*9+k];
  float a1w[8][3], b1w[8];
#pragma unroll
  for(int c=0;c<8;c++){
    a1w[c][0]=cv_a1[c*3+0]; a1w[c][1]=cv_a1[c*3+1]; a1w[c][2]=cv_a1[c*3+2];
    b1w[c]=cv_b1[c];
  }
  const unsigned short* hrow = hTb + c16*NPTS;
  f32x4v acc = {0.0f,0.0f,0.0f,0.0f};
  wave_lds_fence();

#pragma unroll 1
  for(int jb=jh*2048; jb<jh*2048+2048; jb+=64){
    int j = jb + lane;
    float px=pF[j*3+0], py=pF[j*3+1], pz=pF[j*3+2];
    float nx=nF[j*3+0], ny=nF[j*3+1], nz=nF[j*3+2];
    float dx=px-pix, dy=py-piy, dz=pz-piz;
    float d2=dx*dx+dy*dy+dz*dz;
    float f=2.0f-(nx*nu[0]+ny*nu[1]+nz*nu[2]);
    float win=__expf(-d2*f*f);
    float X0=nu[0]*dx+nu[1]*dy+nu[2]*dz;
    float X1=nu[3]*dx+nu[4]*dy+nu[5]*dz;
    float X2=nu[6]*dx+nu[7]*dy+nu[8]*dz;
    float z[8];
#pragma unroll
    for(int c=0;c<8;c++){
      float r=fmaf(X0,a1w[c][0],fmaf(X1,a1w[c][1],fmaf(X2,a1w[c][2],b1w[c])));
      z[c]=win*fmaxf(r,0.0f);
    }
    zr[0]=pk2(z[0],z[1]); zr[1]=pk2(z[2],z[3]);
    zr[2]=pk2(z[4],z[5]); zr[3]=pk2(z[6],z[7]);
    zr[4]=(unsigned)f2bf(win);
    wave_lds_fence();
#pragma unroll
    for(int q2=0;q2<2;q2++){
      int jb2 = jb + q2*32;
      bf16x8v afr = *(const bf16x8v*)(hrow + jb2 + q*8);
      bf16x8v bfr;
#pragma unroll
      for(int t=0;t<8;t++)
        bfr[t] = __builtin_bit_cast(__bf16, zs[w][q2*32 + q*8 + t][c16]);
      acc = __builtin_amdgcn_mfma_f32_16x16x32_bf16(afr, bfr, acc, 0, 0, 0);
    }
    wave_lds_fence();
  }
  // combine j-halves, then epilogue (C/D: col=lane&15, row=q*4+r)
#pragma unroll
  for(int r=0;r<4;r++) red[w][lane][r]=acc[r];
  __syncthreads();
  if(jh==0){
#pragma unroll
    for(int r=0;r<4;r++){
      int h = q*4 + r;
      float coef = (c16<8) ? cv_a2[h*8+c16] : ((c16==8) ? cv_b2[h] : 0.0f);
      float v = (red[w][lane][r]+red[w+1][lane][r])*coef;
#pragma unroll
      for(int o=1;o<16;o<<=1) v += __shfl_xor(v,o);
      if(c16==0) xiF[i*16+h]=v;
    }
  }
}

// ---- k6a ----
__global__ __launch_bounds__(256) void k6a(const float* __restrict__ xiF,
    const float* no_w1, const float* no_b1, const float* no_w2, const float* no_b2,
    float* __restrict__ tF, float* __restrict__ stats2){
  int i = blockIdx.x*256 + threadIdx.x;
  int lane = threadIdx.x & 63;
  float xi[16];
#pragma unroll
  for(int k=0;k<16;k++) xi[k]=xiF[i*16+k];
  float t1[16];
#pragma unroll
  for(int o=0;o<16;o++){
    float t=ldb(no_b1,o);
#pragma unroll
    for(int k=0;k<16;k++) t += xi[k]*ldb(no_w1,o*16+k);
    t1[o]=lk(t);
  }
  float t2[16];
#pragma unroll
  for(int o=0;o<16;o++){
    float t=ldb(no_b2,o);
#pragma unroll
    for(int k=0;k<16;k++) t += t1[k]*ldb(no_w2,o*16+k);
    t2[o]=lk(t);
    tF[i*16+o]=t2[o];
  }
  float gs[4]={0,0,0,0}, gq[4]={0,0,0,0};
#pragma unroll
  for(int c=0;c<16;c++){ gs[c>>2]+=t2[c]; gq[c>>2]+=t2[c]*t2[c]; }
  __shared__ float ls[8];
  if(threadIdx.x<8) ls[threadIdx.x]=0.0f;
  __syncthreads();
#pragma unroll
  for(int g=0;g<4;g++){ gs[g]=wsum64(gs[g]); gq[g]=wsum64(gq[g]); }
  if(lane==0){
#pragma unroll
    for(int g=0;g<4;g++){ atomicAdd(&ls[2*g],gs[g]); atomicAdd(&ls[2*g+1],gq[g]); }
  }
  __syncthreads();
  if(threadIdx.x<8) atomicAdd(&stats2[threadIdx.x], ls[threadIdx.x]);
}

// ---- k6c ----
__global__ __launch_bounds__(256) void k6c(const float* __restrict__ tF,
    const float* __restrict__ xfF, const float* __restrict__ stats2,
    const float* gw, const float* gb,
    const float* ll_w1, const float* ll_b1, const float* ll_w2, const float* ll_b2,
    const float* lt_w, const float* lt_b,
    float* __restrict__ out){
  int i = blockIdx.x*256 + threadIdx.x;
  float m[4], r[4];
#pragma unroll
  for(int g=0;g<4;g++){
    float mean = stats2[2*g]*(1.0f/(4.0f*NPTS));
    float var  = stats2[2*g+1]*(1.0f/(4.0f*NPTS)) - mean*mean;
    m[g]=mean; r[g]=1.0f/sqrtf(var+1e-5f);
  }
  float tn[16];
#pragma unroll
  for(int c=0;c<16;c++){
    int g=c>>2;
    tn[c]=(tF[i*16+c]-m[g])*r[g]*ldb(gw,c)+ldb(gb,c);
  }
  float z1[16];
#pragma unroll
  for(int o=0;o<16;o++){
    float t=ldb(ll_b1,o);
#pragma unroll
    for(int k=0;k<16;k++) t += tn[k]*ldb(ll_w1,o*16+k);
    z1[o]=fmaxf(t,0.0f);
  }
  float xf[DINF];
#pragma unroll
  for(int k=0;k<DINF;k++) xf[k]=xfF[i*DINF+k];
#pragma unroll
  for(int o=0;o<16;o++){
    float z=ldb(ll_b2,o);
#pragma unroll
    for(int k=0;k<16;k++) z += z1[k]*ldb(ll_w2,o*16+k);
    float lt=ldb(lt_b,o);
#pragma unroll
    for(int k=0;k<DINF;k++) lt += xf[k]*ldb(lt_w,o*DINF+k);
    out[i*16+o]=z+lt;
  }
}

extern "C" void kernel_launch(void* const* d_in, const int* in_sizes, int n_in,
                              void* d_out, int out_size, void* d_ws, size_t ws_size,
                              hipStream_t stream){
  const float* verts    = (const float*)d_in[0];
  const float* vnormals = (const float*)d_in[1];
  const float* x        = (const float*)d_in[2];
  const float* os_w1    = (const float*)d_in[3];
  const float* os_b1    = (const float*)d_in[4];
  const float* os_w2    = (const float*)d_in[5];
  const float* os_b2    = (const float*)d_in[6];
  const float* ni_w1    = (const float*)d_in[7];
  const float* ni_b1    = (const float*)d_in[8];
  const float* ni_w2    = (const float*)d_in[9];
  const float* ni_b2    = (const float*)d_in[10];
  const float* gn_in_w  = (const float*)d_in[11];
  const float* gn_in_b  = (const float*)d_in[12];
  const float* cv_a1    = (const float*)d_in[13];
  const float* cv_b1    = (const float*)d_in[14];
  const float* cv_a2    = (const float*)d_in[15];
  const float* cv_b2    = (const float*)d_in[16];
  const float* no_w1    = (const float*)d_in[17];
  const float* no_b1    = (const float*)d_in[18];
  const float* no_w2    = (const float*)d_in[19];
  const float* no_b2    = (const float*)d_in[20];
  const float* gn_out_w = (const float*)d_in[21];
  const float* gn_out_b = (const float*)d_in[22];
  const float* ll_w1    = (const float*)d_in[23];
  const float* ll_b1    = (const float*)d_in[24];
  const float* ll_w2    = (const float*)d_in[25];
  const float* ll_b2    = (const float*)d_in[26];
  const float* lt_w     = (const float*)d_in[27];
  const float* lt_b     = (const float*)d_in[28];

  float* W = (float*)d_ws;
  size_t off = 0;
  float* vertsF = W + off; off += (size_t)3*NPTS;
  float* nF     = W + off; off += (size_t)3*NPTS;
  float* pF     = W + off; off += (size_t)3*NPTS;
  float* xfF    = W + off; off += (size_t)DINF*NPTS;
  float* sc     = W + off; off += (size_t)13*NPTS*5;
  float* wOS    = W + off; off += (size_t)NPTS;
  float* hPre   = W + off; off += (size_t)16*NPTS;
  unsigned short* hTb = (unsigned short*)(W + off); off += (size_t)8*NPTS;
  float* nuvF   = W + off; off += (size_t)9*NPTS;
  float* xiF    = W + off; off += (size_t)16*NPTS;
  float* tF     = W + off; off += (size_t)16*NPTS;
  float* stats  = W + off; off += 16;
  // mom2 (5*12*NPTS floats) aliased onto [hPre..) — dead until k3 writes hPre,
  // and k2s (its last reader) completes before k3 in stream order.
  float* mom2 = hPre;

  hipMemsetAsync(stats, 0, 16*sizeof(float), stream);
  hipMemsetAsync(sc,   0, (size_t)13*NPTS*5*sizeof(float), stream);
  hipMemsetAsync(mom2, 0, (size_t)12*NPTS*5*sizeof(float), stream);

  k0_convert<<<NPTS/256, 256, 0, stream>>>(verts, vnormals, x, vertsF, nF, pF, xfF);
  k1m<<<NPTS/8, 512, 0, stream>>>(vertsF, nF, sc);
  k2m<<<NPTS/8, 512, 0, stream>>>(vertsF, sc, mom2);
  k2s<<<5*NPTS/256, 256, 0, stream>>>(vertsF, sc, mom2, xfF);
  k3_mlps<<<NPTS/256, 256, 0, stream>>>(xfF, os_w1, os_b1, os_w2, os_b2,
                                        ni_w1, ni_b1, ni_w2, ni_b2, wOS, hPre, stats);
  k3c_gn<<<NPTS/256, 256, 0, stream>>>(hPre, stats, gn_in_w, gn_in_b, hTb);
  k4_ov<<<NPTS/2, 256, 0, stream>>>(pF, nF, wOS, nuvF);
  k5_conv<<<NPTS/2, 256, 0, stream>>>(pF, nF, nuvF, hTb, cv_a1, cv_b1, cv_a2, cv_b2, xiF);
  k6a<<<NPTS/256, 256, 0, stream>>>(xiF, no_w1, no_b1, no_w2, no_b2, tF, stats+8);
  k6c<<<NPTS/256, 256, 0, stream>>>(tF, xfF, stats+8, gn_out_w, gn_out_b,
                                    ll_w1, ll_b1, ll_w2, ll_b2, lt_w, lt_b, (float*)d_out);
}

// Round 9
// 342.200 us; speedup vs baseline: 1.0068x; 1.0068x over previous
//
#include <hip/hip_runtime.h>
#include <hip/hip_bf16.h>
#include <math.h>

#define NPTS 4096
#define DINF 26
#define LOG2E 1.44269504088896f
#define CSTR 72   // col stride in shorts (144B: 16B-aligned, bank-spread)

typedef float f32x4v __attribute__((ext_vector_type(4)));
typedef __bf16 bf16x8v __attribute__((ext_vector_type(8)));

__device__ __forceinline__ float ldb(const float* p, int i){ return p[i]; }
__device__ __forceinline__ float lk(float v){ return v >= 0.0f ? v : 0.2f*v; }
__device__ __forceinline__ float wsum64(float v){
#pragma unroll
  for(int o=32;o>0;o>>=1) v += __shfl_down(v,o);
  return v;
}
__device__ __forceinline__ unsigned short f2bf(float f){
  return __builtin_bit_cast(unsigned short, __float2bfloat16(f));
}
__device__ __forceinline__ float bf2f(unsigned short u){
  return __bfloat162float(__builtin_bit_cast(__hip_bfloat16, u));
}
// intra-wave LDS write->read ordering (DS pipe in-order per wave; stops
// compiler pipelining across the exchange — R3/R4 lesson).
__device__ __forceinline__ void wave_lds_fence(){
  __builtin_amdgcn_wave_barrier();
  __builtin_amdgcn_s_waitcnt(0xC07F);   // lgkmcnt(0)
  __builtin_amdgcn_wave_barrier();
}
__device__ __forceinline__ void tangent(float nx,float ny,float nz,float* t1,float* t2){
  float s = (nz >= 0.0f) ? 1.0f : -1.0f;
  float a = -1.0f/(s+nz);
  float b = nx*ny*a;
  t1[0]=1.0f+s*nx*nx*a; t1[1]=s*b; t1[2]=-s*nx;
  t2[0]=b; t2[1]=s+ny*ny*a; t2[2]=-ny;
}

// ---- k0 ----
__global__ __launch_bounds__(256) void k0_convert(const float* __restrict__ verts,
                                                  const float* __restrict__ vnorm,
                                                  const float* __restrict__ x,
                                                  float* __restrict__ vertsF,
                                                  float* __restrict__ nF,
                                                  float* __restrict__ pF,
                                                  float* __restrict__ xfF){
  int i = blockIdx.x*blockDim.x + threadIdx.x;
  if(i >= NPTS) return;
#pragma unroll
  for(int d=0;d<3;d++){
    float v = verts[i*3+d];
    vertsF[i*3+d]=v;
    pF[i*3+d]=v*(1.0f/9.0f);
    nF[i*3+d]=vnorm[i*3+d];
  }
#pragma unroll
  for(int c=0;c<16;c++) xfF[i*DINF+c]=x[i*16+c];
}

// ---- k1m: pass-1 moments via MFMA; col-major hi/lo LDS (b128 B reads) ------
// cols: 0=1, 1..3=v, 4..9=xx xy xz yy yz zz, 10..12=n, 13..15=0
__global__ __launch_bounds__(512) void k1m(const float* __restrict__ vertsF,
                                           const float* __restrict__ nF,
                                           float* __restrict__ sc){
  __shared__ __align__(16) unsigned short fbh[8][16][CSTR];
  __shared__ __align__(16) unsigned short fbl[8][16][CSTR];
  __shared__ __align__(16) float vq[8][64][4];
  __shared__ float red[8][16][16];
  const float c2e[5] = {0.5f*LOG2E, 0.125f*LOG2E, (1.0f/18.0f)*LOG2E,
                        0.02f*LOG2E, 0.005f*LOG2E};
  int lane = threadIdx.x & 63, w = threadIdx.x >> 6;
  int c16 = lane & 15, q = lane >> 4;
  int it = blockIdx.x >> 1, jh = blockIdx.x & 1;
  int i0 = it*16;
  int ia = i0 + c16;
  float vix=vertsF[ia*3+0], viy=vertsF[ia*3+1], viz=vertsF[ia*3+2];
  float nsqi = vix*vix+viy*viy+viz*viz;
  // constant col0 (value 1.0) + zero cols 13..15, once
  fbh[w][0][lane]=0x3F80u; fbl[w][0][lane]=0u;
#pragma unroll
  for(int c=13;c<16;c++){ fbh[w][c][lane]=0u; fbl[w][c][lane]=0u; }
  f32x4v acc[5];
#pragma unroll
  for(int s=0;s<5;s++) acc[s] = (f32x4v){0.0f,0.0f,0.0f,0.0f};

  int jbeg = jh*2048 + w*256;
#pragma unroll 1
  for(int jb = jbeg; jb < jbeg+256; jb += 64){
    int j = jb + lane;
    float vx=vertsF[j*3+0], vy=vertsF[j*3+1], vz=vertsF[j*3+2];
    float nx=nF[j*3+0], ny=nF[j*3+1], nz=nF[j*3+2];
    float nsq = vx*vx+vy*vy+vz*vz;
    float fv[13];
    fv[1]=vx; fv[2]=vy; fv[3]=vz;
    fv[4]=vx*vx; fv[5]=vx*vy; fv[6]=vx*vz; fv[7]=vy*vy; fv[8]=vy*vz; fv[9]=vz*vz;
    fv[10]=nx; fv[11]=ny; fv[12]=nz;
#pragma unroll
    for(int c=1;c<13;c++){
      unsigned short h=f2bf(fv[c]);
      fbh[w][c][lane]=h;
      fbl[w][c][lane]=f2bf(fv[c]-bf2f(h));
    }
    *(float4*)&vq[w][lane][0] = make_float4(vx,vy,vz,nsq);
    wave_lds_fence();
#pragma unroll
    for(int q2=0;q2<2;q2++){
      int rb = q2*32 + q*8;
      bf16x8v bh = *(const bf16x8v*)&fbh[w][c16][rb];
      bf16x8v bl = *(const bf16x8v*)&fbl[w][c16][rb];
      bf16x8v af[5];
#pragma unroll
      for(int t=0;t<8;t++){
        float4 vv = *(const float4*)&vq[w][rb+t][0];
        float dot = vix*vv.x + viy*vv.y + viz*vv.z;
        float d2 = fmaxf(nsqi + vv.w - 2.0f*dot, 0.0f);
#pragma unroll
        for(int s=0;s<5;s++)
          af[s][t] = __builtin_bit_cast(__bf16, f2bf(exp2f(-d2*c2e[s])));
      }
#pragma unroll
      for(int s=0;s<5;s++){
        acc[s] = __builtin_amdgcn_mfma_f32_16x16x32_bf16(af[s], bh, acc[s], 0,0,0);
        acc[s] = __builtin_amdgcn_mfma_f32_16x16x32_bf16(af[s], bl, acc[s], 0,0,0);
      }
    }
    wave_lds_fence();
  }
  // 8-wave reduce, atomic-accumulate moments
#pragma unroll
  for(int s=0;s<5;s++){
#pragma unroll
    for(int r=0;r<4;r++) red[w][q*4+r][c16] = acc[s][r];
    __syncthreads();
    if(w==0){
      float* base = sc + (size_t)s*13*NPTS;
#pragma unroll
      for(int r=0;r<4;r++){
        int m = q*4+r, i = i0+m;
        float D = 0.0f;
#pragma unroll
        for(int ww=0;ww<8;ww++) D += red[ww][m][c16];
        if(c16==0)       atomicAdd(&base[i], D);
        else if(c16<4)   atomicAdd(&base[NPTS + i*3 + (c16-1)], D);
        else if(c16<10)  atomicAdd(&base[4*NPTS + i*6 + (c16-4)], D);
        else if(c16<13)  atomicAdd(&base[10*NPTS + i*3 + (c16-10)], D);
      }
    }
    __syncthreads();
  }
}

// ---- k2m: pass-2 moments via MFMA; col-major hi/lo (b128 B reads) ----------
// cols: 0..2=ns, 3..11=v⊗ns row-major, 12..15=0
__global__ __launch_bounds__(512) void k2m(const float* __restrict__ vertsF,
                                           const float* __restrict__ sc,
                                           float* __restrict__ mom2){
  __shared__ __align__(16) unsigned short fbh[8][16][CSTR];
  __shared__ __align__(16) unsigned short fbl[8][16][CSTR];
  __shared__ __align__(16) float vq[8][64][4];
  __shared__ float red[8][16][16];
  const float c2e[5] = {0.5f*LOG2E, 0.125f*LOG2E, (1.0f/18.0f)*LOG2E,
                        0.02f*LOG2E, 0.005f*LOG2E};
  int lane = threadIdx.x & 63, w = threadIdx.x >> 6;
  int c16 = lane & 15, q = lane >> 4;
  int it = blockIdx.x >> 1, jh = blockIdx.x & 1;
  int i0 = it*16;
  int ia = i0 + c16;
  float vix=vertsF[ia*3+0], viy=vertsF[ia*3+1], viz=vertsF[ia*3+2];
  float nsqi = vix*vix+viy*viy+viz*viz;
#pragma unroll
  for(int c=12;c<16;c++){ fbh[w][c][lane]=0u; fbl[w][c][lane]=0u; }
  f32x4v acc[5];
#pragma unroll
  for(int s=0;s<5;s++) acc[s] = (f32x4v){0.0f,0.0f,0.0f,0.0f};

  int jbeg = jh*2048 + w*256;
#pragma unroll 1
  for(int jb = jbeg; jb < jbeg+256; jb += 64){
    int j = jb + lane;
    float vx=vertsF[j*3+0], vy=vertsF[j*3+1], vz=vertsF[j*3+2];
    float nsq = vx*vx+vy*vy+vz*vz;
    *(float4*)&vq[w][lane][0] = make_float4(vx,vy,vz,nsq);
    wave_lds_fence();
    float d2c[2][8];
#pragma unroll
    for(int q2=0;q2<2;q2++)
#pragma unroll
      for(int t=0;t<8;t++){
        float4 vv = *(const float4*)&vq[w][q2*32+q*8+t][0];
        float dot = vix*vv.x + viy*vv.y + viz*vv.z;
        d2c[q2][t] = fmaxf(nsqi + vv.w - 2.0f*dot, 0.0f);
      }
    wave_lds_fence();
#pragma unroll
    for(int s=0;s<5;s++){
      const float* ub = sc + (size_t)s*13*NPTS + 10*NPTS + (size_t)j*3;
      float ux=ub[0], uy=ub[1], uz=ub[2];
      float inv = 1.0f/fmaxf(sqrtf(ux*ux+uy*uy+uz*uz), 1e-12f);
      float n0=ux*inv, n1=uy*inv, n2=uz*inv;
      float fv[12];
      fv[0]=n0; fv[1]=n1; fv[2]=n2;
      fv[3]=vx*n0; fv[4]=vx*n1; fv[5]=vx*n2;
      fv[6]=vy*n0; fv[7]=vy*n1; fv[8]=vy*n2;
      fv[9]=vz*n0; fv[10]=vz*n1; fv[11]=vz*n2;
#pragma unroll
      for(int c=0;c<12;c++){
        unsigned short h=f2bf(fv[c]);
        fbh[w][c][lane]=h;
        fbl[w][c][lane]=f2bf(fv[c]-bf2f(h));
      }
      wave_lds_fence();
#pragma unroll
      for(int q2=0;q2<2;q2++){
        int rb = q2*32 + q*8;
        bf16x8v bh = *(const bf16x8v*)&fbh[w][c16][rb];
        bf16x8v bl = *(const bf16x8v*)&fbl[w][c16][rb];
        bf16x8v af;
#pragma unroll
        for(int t=0;t<8;t++)
          af[t] = __builtin_bit_cast(__bf16, f2bf(exp2f(-d2c[q2][t]*c2e[s])));
        acc[s] = __builtin_amdgcn_mfma_f32_16x16x32_bf16(af, bh, acc[s], 0,0,0);
        acc[s] = __builtin_amdgcn_mfma_f32_16x16x32_bf16(af, bl, acc[s], 0,0,0);
      }
      wave_lds_fence();
    }
  }
#pragma unroll
  for(int s=0;s<5;s++){
#pragma unroll
    for(int r=0;r<4;r++) red[w][q*4+r][c16] = acc[s][r];
    __syncthreads();
    if(w==0){
#pragma unroll
      for(int r=0;r<4;r++){
        int m = q*4+r, i = i0+m;
        float D = 0.0f;
#pragma unroll
        for(int ww=0;ww<8;ww++) D += red[ww][m][c16];
        if(c16<12) atomicAdd(&mom2[((size_t)s*NPTS + i)*12 + c16], D);
      }
    }
    __syncthreads();
  }
}

// ---- k2s: per-(i,scale) curvature solve ------------------------------------
__global__ __launch_bounds__(256) void k2s(const float* __restrict__ vertsF,
                                           const float* __restrict__ sc,
                                           const float* __restrict__ mom2,
                                           float* __restrict__ xfF){
  int idx = blockIdx.x*256 + threadIdx.x;      // 20480 = 5*4096
  int i = idx & (NPTS-1);
  int s = idx >> 12;
  const float* base = sc + (size_t)s*13*NPTS;
  float v[3] = { vertsF[i*3+0], vertsF[i*3+1], vertsF[i*3+2] };
  float s0 = base[i];
  float sx[3] = { base[NPTS+i*3+0], base[NPTS+i*3+1], base[NPTS+i*3+2] };
  float sxx6[6];
#pragma unroll
  for(int k=0;k<6;k++) sxx6[k]=base[4*NPTS+i*6+k];
  float ux=base[10*NPTS+i*3+0], uy=base[10*NPTS+i*3+1], uz=base[10*NPTS+i*3+2];
  float invn = 1.0f/fmaxf(sqrtf(ux*ux+uy*uy+uz*uz), 1e-12f);
  float nsi[3] = { ux*invn, uy*invn, uz*invn };
  const float* M2 = mom2 + ((size_t)s*NPTS + i)*12;
  float sn[3] = { M2[0], M2[1], M2[2] };
  float sxn[3][3];
#pragma unroll
  for(int a=0;a<3;a++)
#pragma unroll
    for(int b=0;b<3;b++) sxn[a][b]=M2[3+a*3+b];
  const int m6[3][3]={{0,1,2},{1,3,4},{2,4,5}};
  float cxx[3][3], cxn[3][3];
#pragma unroll
  for(int a=0;a<3;a++)
#pragma unroll
    for(int b=0;b<3;b++){
      cxx[a][b]=sxx6[m6[a][b]] - v[a]*sx[b] - sx[a]*v[b] + s0*v[a]*v[b];
      cxn[a][b]=sxn[a][b]    - v[a]*sn[b] - sx[a]*nsi[b] + s0*v[a]*nsi[b];
    }
  float t1[3],t2[3];
  tangent(nsi[0],nsi[1],nsi[2],t1,t2);
  float ppt[2][2], pqt[2][2];
#pragma unroll
  for(int k=0;k<2;k++){
    const float* tk = (k==0)?t1:t2;
#pragma unroll
    for(int l=0;l<2;l++){
      const float* tl = (l==0)?t1:t2;
      float accx=0.0f, accn=0.0f;
#pragma unroll
      for(int a=0;a<3;a++)
#pragma unroll
        for(int b=0;b<3;b++){
          accx += tk[a]*cxx[a][b]*tl[b];
          accn += tk[a]*cxn[a][b]*tl[b];
        }
      ppt[k][l]=accx + ((k==l)?0.01f:0.0f);
      pqt[k][l]=accn;
    }
  }
  float det = ppt[0][0]*ppt[1][1]-ppt[0][1]*ppt[1][0];
  float id = 1.0f/det;
  float S00=( ppt[1][1]*pqt[0][0]-ppt[0][1]*pqt[1][0])*id;
  float S01=( ppt[1][1]*pqt[0][1]-ppt[0][1]*pqt[1][1])*id;
  float S10=(-ppt[1][0]*pqt[0][0]+ppt[0][0]*pqt[1][0])*id;
  float S11=(-ppt[1][0]*pqt[0][1]+ppt[0][0]*pqt[1][1])*id;
  float f0=fminf(fmaxf(S00+S11,-1.0f),1.0f);
  float f1=fminf(fmaxf(S00*S11-S01*S10,-1.0f),1.0f);
  xfF[i*DINF+16+2*s]=f0;
  xfF[i*DINF+17+2*s]=f1;
}

// ---- k3 ----
__global__ __launch_bounds__(256) void k3_mlps(const float* __restrict__ xfF,
    const float* os_w1, const float* os_b1, const float* os_w2, const float* os_b2,
    const float* ni_w1, const float* ni_b1, const float* ni_w2, const float* ni_b2,
    float* __restrict__ wOS, float* __restrict__ hPre, float* __restrict__ stats){
  int i = blockIdx.x*256 + threadIdx.x;
  int lane = threadIdx.x & 63;
  float xf[DINF];
#pragma unroll
  for(int k=0;k<DINF;k++) xf[k]=xfF[i*DINF+k];
  float h1[16];
#pragma unroll
  for(int o=0;o<16;o++){
    float t=ldb(os_b1,o);
#pragma unroll
    for(int k=0;k<DINF;k++) t += xf[k]*ldb(os_w1,o*DINF+k);
    h1[o]=lk(t);
  }
  float w=ldb(os_b2,0);
#pragma unroll
  for(int o=0;o<16;o++) w += h1[o]*ldb(os_w2,o);
  wOS[i]=w;
#pragma unroll
  for(int o=0;o<16;o++){
    float t=ldb(ni_b1,o);
#pragma unroll
    for(int k=0;k<DINF;k++) t += xf[k]*ldb(ni_w1,o*DINF+k);
    h1[o]=lk(t);
  }
  float h2[16];
#pragma unroll
  for(int o=0;o<16;o++){
    float t=ldb(ni_b2,o);
#pragma unroll
    for(int k=0;k<16;k++) t += h1[k]*ldb(ni_w2,o*16+k);
    h2[o]=lk(t);
    hPre[i*16+o]=h2[o];
  }
  float gs[4]={0,0,0,0}, gq[4]={0,0,0,0};
#pragma unroll
  for(int c=0;c<16;c++){ gs[c>>2]+=h2[c]; gq[c>>2]+=h2[c]*h2[c]; }
  __shared__ float ls[8];
  if(threadIdx.x<8) ls[threadIdx.x]=0.0f;
  __syncthreads();
#pragma unroll
  for(int g=0;g<4;g++){ gs[g]=wsum64(gs[g]); gq[g]=wsum64(gq[g]); }
  if(lane==0){
#pragma unroll
    for(int g=0;g<4;g++){ atomicAdd(&ls[2*g],gs[g]); atomicAdd(&ls[2*g+1],gq[g]); }
  }
  __syncthreads();
  if(threadIdx.x<8) atomicAdd(&stats[threadIdx.x], ls[threadIdx.x]);
}

// ---- k3c: GN -> bf16 transposed hTb[16][4096] ----
__global__ __launch_bounds__(256) void k3c_gn(const float* __restrict__ hPre,
                                              const float* __restrict__ stats,
                                              const float* gw, const float* gb,
                                              unsigned short* __restrict__ hTb){
  int i = blockIdx.x*256 + threadIdx.x;
  float m[4], r[4];
#pragma unroll
  for(int g=0;g<4;g++){
    float mean = stats[2*g]*(1.0f/(4.0f*NPTS));
    float var  = stats[2*g+1]*(1.0f/(4.0f*NPTS)) - mean*mean;
    m[g]=mean; r[g]=1.0f/sqrtf(var+1e-5f);
  }
#pragma unroll
  for(int c=0;c<16;c++){
    int g=c>>2;
    float v=(hPre[i*16+c]-m[g])*r[g]*ldb(gw,c)+ldb(gb,c);
    hTb[c*NPTS+i]=f2bf(v);
  }
}

// ---- k4: 2-way j split per i -----------------------------------------------
__global__ __launch_bounds__(256) void k4_ov(const float* __restrict__ pF,
                                             const float* __restrict__ nF,
                                             const float* __restrict__ wOS,
                                             float* __restrict__ nuvF){
  __shared__ float part[4][4];
  int lane = threadIdx.x & 63;
  int w = threadIdx.x >> 6;
  int ii = w >> 1, jh = w & 1;
  int i = blockIdx.x*2 + ii;
  float pix=pF[i*3+0], piy=pF[i*3+1], piz=pF[i*3+2];
  float nix=nF[i*3+0], niy=nF[i*3+1], niz=nF[i*3+2];
  float a0=0,a1=0,a2=0,a3=0;
#pragma unroll 1
  for(int j=jh*2048+lane; j<jh*2048+2048; j+=64){
    float px=pF[j*3+0], py=pF[j*3+1], pz=pF[j*3+2];
    float nx=nF[j*3+0], ny=nF[j*3+1], nz=nF[j*3+2];
    float wj=wOS[j];
    float dx=px-pix, dy=py-piy, dz=pz-piz;
    float d2=dx*dx+dy*dy+dz*dz;
    float f=2.0f-(nx*nix+ny*niy+nz*niz);
    float Wv=__expf(-d2*f*f);
    float Ww=Wv*wj;
    a0+=Ww*px; a1+=Ww*py; a2+=Ww*pz; a3+=Ww;
  }
  a0=wsum64(a0); a1=wsum64(a1); a2=wsum64(a2); a3=wsum64(a3);
  if(lane==0){ part[w][0]=a0; part[w][1]=a1; part[w][2]=a2; part[w][3]=a3; }
  __syncthreads();
  if(lane==0 && jh==0){
    a0=part[w][0]+part[w+1][0]; a1=part[w][1]+part[w+1][1];
    a2=part[w][2]+part[w+1][2]; a3=part[w][3]+part[w+1][3];
    float o0=a0-a3*pix, o1=a1-a3*piy, o2=a2-a3*piz;
    float t1[3],t2[3];
    tangent(nix,niy,niz,t1,t2);
    float ov0=t1[0]*o0+t1[1]*o1+t1[2]*o2+1e-5f;
    float ov1=t2[0]*o0+t2[1]*o1+t2[2]*o2+1e-5f;
    float inv=1.0f/sqrtf(ov0*ov0+ov1*ov1);
    float ex=ov0*inv, ey=ov1*inv;
    nuvF[i*9+0]=nix; nuvF[i*9+1]=niy; nuvF[i*9+2]=niz;
    nuvF[i*9+3]= ex*t1[0]+ey*t2[0]; nuvF[i*9+4]= ex*t1[1]+ey*t2[1]; nuvF[i*9+5]= ex*t1[2]+ey*t2[2];
    nuvF[i*9+6]=-ey*t1[0]+ex*t2[0]; nuvF[i*9+7]=-ey*t1[1]+ex*t2[1]; nuvF[i*9+8]=-ey*t1[2]+ex*t2[2];
  }
}

// ---- k5: conv via MFMA; col-major zs (b128 B reads); 2 waves/i -------------
// zs cols: 0..7 = win*relu(r_c), 8 = win, 9..15 = 0
__global__ __launch_bounds__(256) void k5_conv(const float* __restrict__ pF,
                                               const float* __restrict__ nF,
                                               const float* __restrict__ nuvF,
                                               const unsigned short* __restrict__ hTb,
                                               const float* cv_a1, const float* cv_b1,
                                               const float* cv_a2, const float* cv_b2,
                                               float* __restrict__ xiF){
  __shared__ __align__(16) unsigned short zs[4][16][CSTR];
  __shared__ float red[4][64][4];
  int lane = threadIdx.x & 63;
  int w = threadIdx.x >> 6;
  int ii = w >> 1, jh = w & 1;
  int i = blockIdx.x*2 + ii;
  int c16 = lane & 15, q = lane >> 4;
#pragma unroll
  for(int c=9;c<16;c++) zs[w][c][lane]=0u;

  float pix=pF[i*3+0], piy=pF[i*3+1], piz=pF[i*3+2];
  float nu[9];
#pragma unroll
  for(int k=0;k<9;k++) nu[k]=nuvF[i*9+k];
  float a1w[8][3], b1w[8];
#pragma unroll
  for(int c=0;c<8;c++){
    a1w[c][0]=cv_a1[c*3+0]; a1w[c][1]=cv_a1[c*3+1]; a1w[c][2]=cv_a1[c*3+2];
    b1w[c]=cv_b1[c];
  }
  const unsigned short* hrow = hTb + c16*NPTS;
  f32x4v acc = {0.0f,0.0f,0.0f,0.0f};
  wave_lds_fence();

#pragma unroll 1
  for(int jb=jh*2048; jb<jh*2048+2048; jb+=64){
    int j = jb + lane;
    float px=pF[j*3+0], py=pF[j*3+1], pz=pF[j*3+2];
    float nx=nF[j*3+0], ny=nF[j*3+1], nz=nF[j*3+2];
    float dx=px-pix, dy=py-piy, dz=pz-piz;
    float d2=dx*dx+dy*dy+dz*dz;
    float f=2.0f-(nx*nu[0]+ny*nu[1]+nz*nu[2]);
    float win=__expf(-d2*f*f);
    float X0=nu[0]*dx+nu[1]*dy+nu[2]*dz;
    float X1=nu[3]*dx+nu[4]*dy+nu[5]*dz;
    float X2=nu[6]*dx+nu[7]*dy+nu[8]*dz;
#pragma unroll
    for(int c=0;c<8;c++){
      float r=fmaf(X0,a1w[c][0],fmaf(X1,a1w[c][1],fmaf(X2,a1w[c][2],b1w[c])));
      zs[w][c][lane]=f2bf(win*fmaxf(r,0.0f));
    }
    zs[w][8][lane]=f2bf(win);
    wave_lds_fence();
#pragma unroll
    for(int q2=0;q2<2;q2++){
      int jb2 = jb + q2*32;
      bf16x8v afr = *(const bf16x8v*)(hrow + jb2 + q*8);
      bf16x8v bfr = *(const bf16x8v*)&zs[w][c16][q2*32 + q*8];
      acc = __builtin_amdgcn_mfma_f32_16x16x32_bf16(afr, bfr, acc, 0, 0, 0);
    }
    wave_lds_fence();
  }
  // combine j-halves, then epilogue (C/D: col=lane&15, row=q*4+r)
#pragma unroll
  for(int r=0;r<4;r++) red[w][lane][r]=acc[r];
  __syncthreads();
  if(jh==0){
#pragma unroll
    for(int r=0;r<4;r++){
      int h = q*4 + r;
      float coef = (c16<8) ? cv_a2[h*8+c16] : ((c16==8) ? cv_b2[h] : 0.0f);
      float v = (red[w][lane][r]+red[w+1][lane][r])*coef;
#pragma unroll
      for(int o=1;o<16;o<<=1) v += __shfl_xor(v,o);
      if(c16==0) xiF[i*16+h]=v;
    }
  }
}

// ---- k6a ----
__global__ __launch_bounds__(256) void k6a(const float* __restrict__ xiF,
    const float* no_w1, const float* no_b1, const float* no_w2, const float* no_b2,
    float* __restrict__ tF, float* __restrict__ stats2){
  int i = blockIdx.x*256 + threadIdx.x;
  int lane = threadIdx.x & 63;
  float xi[16];
#pragma unroll
  for(int k=0;k<16;k++) xi[k]=xiF[i*16+k];
  float t1[16];
#pragma unroll
  for(int o=0;o<16;o++){
    float t=ldb(no_b1,o);
#pragma unroll
    for(int k=0;k<16;k++) t += xi[k]*ldb(no_w1,o*16+k);
    t1[o]=lk(t);
  }
  float t2[16];
#pragma unroll
  for(int o=0;o<16;o++){
    float t=ldb(no_b2,o);
#pragma unroll
    for(int k=0;k<16;k++) t += t1[k]*ldb(no_w2,o*16+k);
    t2[o]=lk(t);
    tF[i*16+o]=t2[o];
  }
  float gs[4]={0,0,0,0}, gq[4]={0,0,0,0};
#pragma unroll
  for(int c=0;c<16;c++){ gs[c>>2]+=t2[c]; gq[c>>2]+=t2[c]*t2[c]; }
  __shared__ float ls[8];
  if(threadIdx.x<8) ls[threadIdx.x]=0.0f;
  __syncthreads();
#pragma unroll
  for(int g=0;g<4;g++){ gs[g]=wsum64(gs[g]); gq[g]=wsum64(gq[g]); }
  if(lane==0){
#pragma unroll
    for(int g=0;g<4;g++){ atomicAdd(&ls[2*g],gs[g]); atomicAdd(&ls[2*g+1],gq[g]); }
  }
  __syncthreads();
  if(threadIdx.x<8) atomicAdd(&stats2[threadIdx.x], ls[threadIdx.x]);
}

// ---- k6c ----
__global__ __launch_bounds__(256) void k6c(const float* __restrict__ tF,
    const float* __restrict__ xfF, const float* __restrict__ stats2,
    const float* gw, const float* gb,
    const float* ll_w1, const float* ll_b1, const float* ll_w2, const float* ll_b2,
    const float* lt_w, const float* lt_b,
    float* __restrict__ out){
  int i = blockIdx.x*256 + threadIdx.x;
  float m[4], r[4];
#pragma unroll
  for(int g=0;g<4;g++){
    float mean = stats2[2*g]*(1.0f/(4.0f*NPTS));
    float var  = stats2[2*g+1]*(1.0f/(4.0f*NPTS)) - mean*mean;
    m[g]=mean; r[g]=1.0f/sqrtf(var+1e-5f);
  }
  float tn[16];
#pragma unroll
  for(int c=0;c<16;c++){
    int g=c>>2;
    tn[c]=(tF[i*16+c]-m[g])*r[g]*ldb(gw,c)+ldb(gb,c);
  }
  float z1[16];
#pragma unroll
  for(int o=0;o<16;o++){
    float t=ldb(ll_b1,o);
#pragma unroll
    for(int k=0;k<16;k++) t += tn[k]*ldb(ll_w1,o*16+k);
    z1[o]=fmaxf(t,0.0f);
  }
  float xf[DINF];
#pragma unroll
  for(int k=0;k<DINF;k++) xf[k]=xfF[i*DINF+k];
#pragma unroll
  for(int o=0;o<16;o++){
    float z=ldb(ll_b2,o);
#pragma unroll
    for(int k=0;k<16;k++) z += z1[k]*ldb(ll_w2,o*16+k);
    float lt=ldb(lt_b,o);
#pragma unroll
    for(int k=0;k<DINF;k++) lt += xf[k]*ldb(lt_w,o*DINF+k);
    out[i*16+o]=z+lt;
  }
}

extern "C" void kernel_launch(void* const* d_in, const int* in_sizes, int n_in,
                              void* d_out, int out_size, void* d_ws, size_t ws_size,
                              hipStream_t stream){
  const float* verts    = (const float*)d_in[0];
  const float* vnormals = (const float*)d_in[1];
  const float* x        = (const float*)d_in[2];
  const float* os_w1    = (const float*)d_in[3];
  const float* os_b1    = (const float*)d_in[4];
  const float* os_w2    = (const float*)d_in[5];
  const float* os_b2    = (const float*)d_in[6];
  const float* ni_w1    = (const float*)d_in[7];
  const float* ni_b1    = (const float*)d_in[8];
  const float* ni_w2    = (const float*)d_in[9];
  const float* ni_b2    = (const float*)d_in[10];
  const float* gn_in_w  = (const float*)d_in[11];
  const float* gn_in_b  = (const float*)d_in[12];
  const float* cv_a1    = (const float*)d_in[13];
  const float* cv_b1    = (const float*)d_in[14];
  const float* cv_a2    = (const float*)d_in[15];
  const float* cv_b2    = (const float*)d_in[16];
  const float* no_w1    = (const float*)d_in[17];
  const float* no_b1    = (const float*)d_in[18];
  const float* no_w2    = (const float*)d_in[19];
  const float* no_b2    = (const float*)d_in[20];
  const float* gn_out_w = (const float*)d_in[21];
  const float* gn_out_b = (const float*)d_in[22];
  const float* ll_w1    = (const float*)d_in[23];
  const float* ll_b1    = (const float*)d_in[24];
  const float* ll_w2    = (const float*)d_in[25];
  const float* ll_b2    = (const float*)d_in[26];
  const float* lt_w     = (const float*)d_in[27];
  const float* lt_b     = (const float*)d_in[28];

  float* W = (float*)d_ws;
  size_t off = 0;
  float* vertsF = W + off; off += (size_t)3*NPTS;
  float* nF     = W + off; off += (size_t)3*NPTS;
  float* pF     = W + off; off += (size_t)3*NPTS;
  float* xfF    = W + off; off += (size_t)DINF*NPTS;
  float* sc     = W + off; off += (size_t)13*NPTS*5;
  float* wOS    = W + off; off += (size_t)NPTS;
  float* hPre   = W + off; off += (size_t)16*NPTS;
  unsigned short* hTb = (unsigned short*)(W + off); off += (size_t)8*NPTS;
  float* nuvF   = W + off; off += (size_t)9*NPTS;
  float* xiF    = W + off; off += (size_t)16*NPTS;
  float* tF     = W + off; off += (size_t)16*NPTS;
  float* stats  = W + off; off += 16;
  // mom2 (5*12*NPTS floats) aliased onto [hPre..) — dead until k3 writes hPre,
  // and k2s (its last reader) completes before k3 in stream order.
  float* mom2 = hPre;

  hipMemsetAsync(stats, 0, 16*sizeof(float), stream);
  hipMemsetAsync(sc,   0, (size_t)13*NPTS*5*sizeof(float), stream);
  hipMemsetAsync(mom2, 0, (size_t)12*NPTS*5*sizeof(float), stream);

  k0_convert<<<NPTS/256, 256, 0, stream>>>(verts, vnormals, x, vertsF, nF, pF, xfF);
  k1m<<<NPTS/8, 512, 0, stream>>>(vertsF, nF, sc);
  k2m<<<NPTS/8, 512, 0, stream>>>(vertsF, sc, mom2);
  k2s<<<5*NPTS/256, 256, 0, stream>>>(vertsF, sc, mom2, xfF);
  k3_mlps<<<NPTS/256, 256, 0, stream>>>(xfF, os_w1, os_b1, os_w2, os_b2,
                                        ni_w1, ni_b1, ni_w2, ni_b2, wOS, hPre, stats);
  k3c_gn<<<NPTS/256, 256, 0, stream>>>(hPre, stats, gn_in_w, gn_in_b, hTb);
  k4_ov<<<NPTS/2, 256, 0, stream>>>(pF, nF, wOS, nuvF);
  k5_conv<<<NPTS/2, 256, 0, stream>>>(pF, nF, nuvF, hTb, cv_a1, cv_b1, cv_a2, cv_b2, xiF);
  k6a<<<NPTS/256, 256, 0, stream>>>(xiF, no_w1, no_b1, no_w2, no_b2, tF, stats+8);
  k6c<<<NPTS/256, 256, 0, stream>>>(tF, xfF, stats+8, gn_out_w, gn_out_b,
                                    ll_w1, ll_b1, ll_w2, ll_b2, lt_w, lt_b, (float*)d_out);
}

// Round 10
// 309.665 us; speedup vs baseline: 1.1126x; 1.1051x over previous
//
#include <hip/hip_runtime.h>
#include <hip/hip_bf16.h>
#include <math.h>

#define NPTS 4096
#define DINF 26
#define LOG2E 1.44269504088896f
#define CSTR 72
#define JSPL 4

typedef float f32x4v __attribute__((ext_vector_type(4)));
typedef __bf16 bf16x8v __attribute__((ext_vector_type(8)));

__device__ __forceinline__ float ldb(const float* p, int i){ return p[i]; }
__device__ __forceinline__ float lk(float v){ return v >= 0.0f ? v : 0.2f*v; }
__device__ __forceinline__ float wsum64(float v){
#pragma unroll
  for(int o=32;o>0;o>>=1) v += __shfl_down(v,o);
  return v;
}
__device__ __forceinline__ unsigned short f2bf(float f){
  return __builtin_bit_cast(unsigned short, __float2bfloat16(f));
}
__device__ __forceinline__ float bf2f(unsigned short u){
  return __bfloat162float(__builtin_bit_cast(__hip_bfloat16, u));
}
__device__ __forceinline__ void wave_lds_fence(){
  __builtin_amdgcn_wave_barrier();
  __builtin_amdgcn_s_waitcnt(0xC07F);   // lgkmcnt(0)
  __builtin_amdgcn_wave_barrier();
}
__device__ __forceinline__ void tangent(float nx,float ny,float nz,float* t1,float* t2){
  float s = (nz >= 0.0f) ? 1.0f : -1.0f;
  float a = -1.0f/(s+nz);
  float b = nx*ny*a;
  t1[0]=1.0f+s*nx*nx*a; t1[1]=s*b; t1[2]=-s*nx;
  t2[0]=b; t2[1]=s+ny*ny*a; t2[2]=-ny;
}

// ---- k0 ----
__global__ __launch_bounds__(256) void k0_convert(const float* __restrict__ verts,
                                                  const float* __restrict__ vnorm,
                                                  const float* __restrict__ x,
                                                  float* __restrict__ vertsF,
                                                  float* __restrict__ nF,
                                                  float* __restrict__ pF,
                                                  float* __restrict__ xfF){
  int i = blockIdx.x*blockDim.x + threadIdx.x;
  if(i >= NPTS) return;
#pragma unroll
  for(int d=0;d<3;d++){
    float v = verts[i*3+d];
    vertsF[i*3+d]=v;
    pF[i*3+d]=v*(1.0f/9.0f);
    nF[i*3+d]=vnorm[i*3+d];
  }
#pragma unroll
  for(int c=0;c<16;c++) xfF[i*DINF+c]=x[i*16+c];
}

// ---- k1m: pass-1 moments via MFMA; col-major hi/lo LDS ------
__global__ __launch_bounds__(512) void k1m(const float* __restrict__ vertsF,
                                           const float* __restrict__ nF,
                                           float* __restrict__ sc){
  __shared__ __align__(16) unsigned short fbh[8][16][CSTR];
  __shared__ __align__(16) unsigned short fbl[8][16][CSTR];
  __shared__ __align__(16) float vq[8][64][4];
  __shared__ float red[8][16][16];
  const float c2e[5] = {0.5f*LOG2E, 0.125f*LOG2E, (1.0f/18.0f)*LOG2E,
                        0.02f*LOG2E, 0.005f*LOG2E};
  int lane = threadIdx.x & 63, w = threadIdx.x >> 6;
  int c16 = lane & 15, q = lane >> 4;
  int it = blockIdx.x >> 1, jh = blockIdx.x & 1;
  int i0 = it*16;
  int ia = i0 + c16;
  float vix=vertsF[ia*3+0], viy=vertsF[ia*3+1], viz=vertsF[ia*3+2];
  float nsqi = vix*vix+viy*viy+viz*viz;
  fbh[w][0][lane]=0x3F80u; fbl[w][0][lane]=0u;
#pragma unroll
  for(int c=13;c<16;c++){ fbh[w][c][lane]=0u; fbl[w][c][lane]=0u; }
  f32x4v acc[5];
#pragma unroll
  for(int s=0;s<5;s++) acc[s] = (f32x4v){0.0f,0.0f,0.0f,0.0f};

  int jbeg = jh*2048 + w*256;
#pragma unroll 1
  for(int jb = jbeg; jb < jbeg+256; jb += 64){
    int j = jb + lane;
    float vx=vertsF[j*3+0], vy=vertsF[j*3+1], vz=vertsF[j*3+2];
    float nx=nF[j*3+0], ny=nF[j*3+1], nz=nF[j*3+2];
    float nsq = vx*vx+vy*vy+vz*vz;
    float fv[13];
    fv[1]=vx; fv[2]=vy; fv[3]=vz;
    fv[4]=vx*vx; fv[5]=vx*vy; fv[6]=vx*vz; fv[7]=vy*vy; fv[8]=vy*vz; fv[9]=vz*vz;
    fv[10]=nx; fv[11]=ny; fv[12]=nz;
#pragma unroll
    for(int c=1;c<13;c++){
      unsigned short h=f2bf(fv[c]);
      fbh[w][c][lane]=h;
      fbl[w][c][lane]=f2bf(fv[c]-bf2f(h));
    }
    *(float4*)&vq[w][lane][0] = make_float4(vx,vy,vz,nsq);
    wave_lds_fence();
#pragma unroll
    for(int q2=0;q2<2;q2++){
      int rb = q2*32 + q*8;
      bf16x8v bh = *(const bf16x8v*)&fbh[w][c16][rb];
      bf16x8v bl = *(const bf16x8v*)&fbl[w][c16][rb];
      bf16x8v af[5];
#pragma unroll
      for(int t=0;t<8;t++){
        float4 vv = *(const float4*)&vq[w][rb+t][0];
        float dot = vix*vv.x + viy*vv.y + viz*vv.z;
        float d2 = fmaxf(nsqi + vv.w - 2.0f*dot, 0.0f);
#pragma unroll
        for(int s=0;s<5;s++)
          af[s][t] = __builtin_bit_cast(__bf16, f2bf(exp2f(-d2*c2e[s])));
      }
#pragma unroll
      for(int s=0;s<5;s++){
        acc[s] = __builtin_amdgcn_mfma_f32_16x16x32_bf16(af[s], bh, acc[s], 0,0,0);
        acc[s] = __builtin_amdgcn_mfma_f32_16x16x32_bf16(af[s], bl, acc[s], 0,0,0);
      }
    }
    wave_lds_fence();
  }
#pragma unroll
  for(int s=0;s<5;s++){
#pragma unroll
    for(int r=0;r<4;r++) red[w][q*4+r][c16] = acc[s][r];
    __syncthreads();
    if(w==0){
      float* base = sc + (size_t)s*13*NPTS;
#pragma unroll
      for(int r=0;r<4;r++){
        int m = q*4+r, i = i0+m;
        float D = 0.0f;
#pragma unroll
        for(int ww=0;ww<8;ww++) D += red[ww][m][c16];
        if(c16==0)       atomicAdd(&base[i], D);
        else if(c16<4)   atomicAdd(&base[NPTS + i*3 + (c16-1)], D);
        else if(c16<10)  atomicAdd(&base[4*NPTS + i*6 + (c16-4)], D);
        else if(c16<13)  atomicAdd(&base[10*NPTS + i*3 + (c16-10)], D);
      }
    }
    __syncthreads();
  }
}

// ---- k2m: pass-2 moments via MFMA; col-major hi/lo ----------
__global__ __launch_bounds__(512) void k2m(const float* __restrict__ vertsF,
                                           const float* __restrict__ sc,
                                           float* __restrict__ mom2){
  __shared__ __align__(16) unsigned short fbh[8][16][CSTR];
  __shared__ __align__(16) unsigned short fbl[8][16][CSTR];
  __shared__ __align__(16) float vq[8][64][4];
  __shared__ float red[8][16][16];
  const float c2e[5] = {0.5f*LOG2E, 0.125f*LOG2E, (1.0f/18.0f)*LOG2E,
                        0.02f*LOG2E, 0.005f*LOG2E};
  int lane = threadIdx.x & 63, w = threadIdx.x >> 6;
  int c16 = lane & 15, q = lane >> 4;
  int it = blockIdx.x >> 1, jh = blockIdx.x & 1;
  int i0 = it*16;
  int ia = i0 + c16;
  float vix=vertsF[ia*3+0], viy=vertsF[ia*3+1], viz=vertsF[ia*3+2];
  float nsqi = vix*vix+viy*viy+viz*viz;
#pragma unroll
  for(int c=12;c<16;c++){ fbh[w][c][lane]=0u; fbl[w][c][lane]=0u; }
  f32x4v acc[5];
#pragma unroll
  for(int s=0;s<5;s++) acc[s] = (f32x4v){0.0f,0.0f,0.0f,0.0f};

  int jbeg = jh*2048 + w*256;
#pragma unroll 1
  for(int jb = jbeg; jb < jbeg+256; jb += 64){
    int j = jb + lane;
    float vx=vertsF[j*3+0], vy=vertsF[j*3+1], vz=vertsF[j*3+2];
    float nsq = vx*vx+vy*vy+vz*vz;
    *(float4*)&vq[w][lane][0] = make_float4(vx,vy,vz,nsq);
    wave_lds_fence();
    float d2c[2][8];
#pragma unroll
    for(int q2=0;q2<2;q2++)
#pragma unroll
      for(int t=0;t<8;t++){
        float4 vv = *(const float4*)&vq[w][q2*32+q*8+t][0];
        float dot = vix*vv.x + viy*vv.y + viz*vv.z;
        d2c[q2][t] = fmaxf(nsqi + vv.w - 2.0f*dot, 0.0f);
      }
    wave_lds_fence();
#pragma unroll
    for(int s=0;s<5;s++){
      const float* ub = sc + (size_t)s*13*NPTS + 10*NPTS + (size_t)j*3;
      float ux=ub[0], uy=ub[1], uz=ub[2];
      float inv = 1.0f/fmaxf(sqrtf(ux*ux+uy*uy+uz*uz), 1e-12f);
      float n0=ux*inv, n1=uy*inv, n2=uz*inv;
      float fv[12];
      fv[0]=n0; fv[1]=n1; fv[2]=n2;
      fv[3]=vx*n0; fv[4]=vx*n1; fv[5]=vx*n2;
      fv[6]=vy*n0; fv[7]=vy*n1; fv[8]=vy*n2;
      fv[9]=vz*n0; fv[10]=vz*n1; fv[11]=vz*n2;
#pragma unroll
      for(int c=0;c<12;c++){
        unsigned short h=f2bf(fv[c]);
        fbh[w][c][lane]=h;
        fbl[w][c][lane]=f2bf(fv[c]-bf2f(h));
      }
      wave_lds_fence();
#pragma unroll
      for(int q2=0;q2<2;q2++){
        int rb = q2*32 + q*8;
        bf16x8v bh = *(const bf16x8v*)&fbh[w][c16][rb];
        bf16x8v bl = *(const bf16x8v*)&fbl[w][c16][rb];
        bf16x8v af;
#pragma unroll
        for(int t=0;t<8;t++)
          af[t] = __builtin_bit_cast(__bf16, f2bf(exp2f(-d2c[q2][t]*c2e[s])));
        acc[s] = __builtin_amdgcn_mfma_f32_16x16x32_bf16(af, bh, acc[s], 0,0,0);
        acc[s] = __builtin_amdgcn_mfma_f32_16x16x32_bf16(af, bl, acc[s], 0,0,0);
      }
      wave_lds_fence();
    }
  }
#pragma unroll
  for(int s=0;s<5;s++){
#pragma unroll
    for(int r=0;r<4;r++) red[w][q*4+r][c16] = acc[s][r];
    __syncthreads();
    if(w==0){
#pragma unroll
      for(int r=0;r<4;r++){
        int m = q*4+r, i = i0+m;
        float D = 0.0f;
#pragma unroll
        for(int ww=0;ww<8;ww++) D += red[ww][m][c16];
        if(c16<12) atomicAdd(&mom2[((size_t)s*NPTS + i)*12 + c16], D);
      }
    }
    __syncthreads();
  }
}

// ---- k2s: per-(i,scale) curvature solve ------------------------------------
__global__ __launch_bounds__(256) void k2s(const float* __restrict__ vertsF,
                                           const float* __restrict__ sc,
                                           const float* __restrict__ mom2,
                                           float* __restrict__ xfF){
  int idx = blockIdx.x*256 + threadIdx.x;
  int i = idx & (NPTS-1);
  int s = idx >> 12;
  const float* base = sc + (size_t)s*13*NPTS;
  float v[3] = { vertsF[i*3+0], vertsF[i*3+1], vertsF[i*3+2] };
  float s0 = base[i];
  float sx[3] = { base[NPTS+i*3+0], base[NPTS+i*3+1], base[NPTS+i*3+2] };
  float sxx6[6];
#pragma unroll
  for(int k=0;k<6;k++) sxx6[k]=base[4*NPTS+i*6+k];
  float ux=base[10*NPTS+i*3+0], uy=base[10*NPTS+i*3+1], uz=base[10*NPTS+i*3+2];
  float invn = 1.0f/fmaxf(sqrtf(ux*ux+uy*uy+uz*uz), 1e-12f);
  float nsi[3] = { ux*invn, uy*invn, uz*invn };
  const float* M2 = mom2 + ((size_t)s*NPTS + i)*12;
  float sn[3] = { M2[0], M2[1], M2[2] };
  float sxn[3][3];
#pragma unroll
  for(int a=0;a<3;a++)
#pragma unroll
    for(int b=0;b<3;b++) sxn[a][b]=M2[3+a*3+b];
  const int m6[3][3]={{0,1,2},{1,3,4},{2,4,5}};
  float cxx[3][3], cxn[3][3];
#pragma unroll
  for(int a=0;a<3;a++)
#pragma unroll
    for(int b=0;b<3;b++){
      cxx[a][b]=sxx6[m6[a][b]] - v[a]*sx[b] - sx[a]*v[b] + s0*v[a]*v[b];
      cxn[a][b]=sxn[a][b]    - v[a]*sn[b] - sx[a]*nsi[b] + s0*v[a]*nsi[b];
    }
  float t1[3],t2[3];
  tangent(nsi[0],nsi[1],nsi[2],t1,t2);
  float ppt[2][2], pqt[2][2];
#pragma unroll
  for(int k=0;k<2;k++){
    const float* tk = (k==0)?t1:t2;
#pragma unroll
    for(int l=0;l<2;l++){
      const float* tl = (l==0)?t1:t2;
      float accx=0.0f, accn=0.0f;
#pragma unroll
      for(int a=0;a<3;a++)
#pragma unroll
        for(int b=0;b<3;b++){
          accx += tk[a]*cxx[a][b]*tl[b];
          accn += tk[a]*cxn[a][b]*tl[b];
        }
      ppt[k][l]=accx + ((k==l)?0.01f:0.0f);
      pqt[k][l]=accn;
    }
  }
  float det = ppt[0][0]*ppt[1][1]-ppt[0][1]*ppt[1][0];
  float id = 1.0f/det;
  float S00=( ppt[1][1]*pqt[0][0]-ppt[0][1]*pqt[1][0])*id;
  float S01=( ppt[1][1]*pqt[0][1]-ppt[0][1]*pqt[1][1])*id;
  float S10=(-ppt[1][0]*pqt[0][0]+ppt[0][0]*pqt[1][0])*id;
  float S11=(-ppt[1][0]*pqt[0][1]+ppt[0][0]*pqt[1][1])*id;
  float f0=fminf(fmaxf(S00+S11,-1.0f),1.0f);
  float f1=fminf(fmaxf(S00*S11-S01*S10,-1.0f),1.0f);
  xfF[i*DINF+16+2*s]=f0;
  xfF[i*DINF+17+2*s]=f1;
}

// ---- k3 ----
__global__ __launch_bounds__(256) void k3_mlps(const float* __restrict__ xfF,
    const float* os_w1, const float* os_b1, const float* os_w2, const float* os_b2,
    const float* ni_w1, const float* ni_b1, const float* ni_w2, const float* ni_b2,
    float* __restrict__ wOS, float* __restrict__ hPre, float* __restrict__ stats){
  int i = blockIdx.x*256 + threadIdx.x;
  int lane = threadIdx.x & 63;
  float xf[DINF];
#pragma unroll
  for(int k=0;k<DINF;k++) xf[k]=xfF[i*DINF+k];
  float h1[16];
#pragma unroll
  for(int o=0;o<16;o++){
    float t=ldb(os_b1,o);
#pragma unroll
    for(int k=0;k<DINF;k++) t += xf[k]*ldb(os_w1,o*DINF+k);
    h1[o]=lk(t);
  }
  float w=ldb(os_b2,0);
#pragma unroll
  for(int o=0;o<16;o++) w += h1[o]*ldb(os_w2,o);
  wOS[i]=w;
#pragma unroll
  for(int o=0;o<16;o++){
    float t=ldb(ni_b1,o);
#pragma unroll
    for(int k=0;k<DINF;k++) t += xf[k]*ldb(ni_w1,o*DINF+k);
    h1[o]=lk(t);
  }
  float h2[16];
#pragma unroll
  for(int o=0;o<16;o++){
    float t=ldb(ni_b2,o);
#pragma unroll
    for(int k=0;k<16;k++) t += h1[k]*ldb(ni_w2,o*16+k);
    h2[o]=lk(t);
    hPre[i*16+o]=h2[o];
  }
  float gs[4]={0,0,0,0}, gq[4]={0,0,0,0};
#pragma unroll
  for(int c=0;c<16;c++){ gs[c>>2]+=h2[c]; gq[c>>2]+=h2[c]*h2[c]; }
  __shared__ float ls[8];
  if(threadIdx.x<8) ls[threadIdx.x]=0.0f;
  __syncthreads();
#pragma unroll
  for(int g=0;g<4;g++){ gs[g]=wsum64(gs[g]); gq[g]=wsum64(gq[g]); }
  if(lane==0){
#pragma unroll
    for(int g=0;g<4;g++){ atomicAdd(&ls[2*g],gs[g]); atomicAdd(&ls[2*g+1],gq[g]); }
  }
  __syncthreads();
  if(threadIdx.x<8) atomicAdd(&stats[threadIdx.x], ls[threadIdx.x]);
}

// ---- k3c: GN -> bf16 transposed hTb[16][4096] ----
__global__ __launch_bounds__(256) void k3c_gn(const float* __restrict__ hPre,
                                              const float* __restrict__ stats,
                                              const float* gw, const float* gb,
                                              unsigned short* __restrict__ hTb){
  int i = blockIdx.x*256 + threadIdx.x;
  float m[4], r[4];
#pragma unroll
  for(int g=0;g<4;g++){
    float mean = stats[2*g]*(1.0f/(4.0f*NPTS));
    float var  = stats[2*g+1]*(1.0f/(4.0f*NPTS)) - mean*mean;
    m[g]=mean; r[g]=1.0f/sqrtf(var+1e-5f);
  }
#pragma unroll
  for(int c=0;c<16;c++){
    int g=c>>2;
    float v=(hPre[i*16+c]-m[g])*r[g]*ldb(gw,c)+ldb(gb,c);
    hTb[c*NPTS+i]=f2bf(v);
  }
}

// ---- k4: 2-way j split per i -----------------------------------------------
__global__ __launch_bounds__(256) void k4_ov(const float* __restrict__ pF,
                                             const float* __restrict__ nF,
                                             const float* __restrict__ wOS,
                                             float* __restrict__ nuvF){
  __shared__ float part[4][4];
  int lane = threadIdx.x & 63;
  int w = threadIdx.x >> 6;
  int ii = w >> 1, jh = w & 1;
  int i = blockIdx.x*2 + ii;
  float pix=pF[i*3+0], piy=pF[i*3+1], piz=pF[i*3+2];
  float nix=nF[i*3+0], niy=nF[i*3+1], niz=nF[i*3+2];
  float a0=0,a1=0,a2=0,a3=0;
#pragma unroll 1
  for(int j=jh*2048+lane; j<jh*2048+2048; j+=64){
    float px=pF[j*3+0], py=pF[j*3+1], pz=pF[j*3+2];
    float nx=nF[j*3+0], ny=nF[j*3+1], nz=nF[j*3+2];
    float wj=wOS[j];
    float dx=px-pix, dy=py-piy, dz=pz-piz;
    float d2=dx*dx+dy*dy+dz*dz;
    float f=2.0f-(nx*nix+ny*niy+nz*niz);
    float Wv=__expf(-d2*f*f);
    float Ww=Wv*wj;
    a0+=Ww*px; a1+=Ww*py; a2+=Ww*pz; a3+=Ww;
  }
  a0=wsum64(a0); a1=wsum64(a1); a2=wsum64(a2); a3=wsum64(a3);
  if(lane==0){ part[w][0]=a0; part[w][1]=a1; part[w][2]=a2; part[w][3]=a3; }
  __syncthreads();
  if(lane==0 && jh==0){
    a0=part[w][0]+part[w+1][0]; a1=part[w][1]+part[w+1][1];
    a2=part[w][2]+part[w+1][2]; a3=part[w][3]+part[w+1][3];
    float o0=a0-a3*pix, o1=a1-a3*piy, o2=a2-a3*piz;
    float t1[3],t2[3];
    tangent(nix,niy,niz,t1,t2);
    float ov0=t1[0]*o0+t1[1]*o1+t1[2]*o2+1e-5f;
    float ov1=t2[0]*o0+t2[1]*o1+t2[2]*o2+1e-5f;
    float inv=1.0f/sqrtf(ov0*ov0+ov1*ov1);
    float ex=ov0*inv, ey=ov1*inv;
    nuvF[i*9+0]=nix; nuvF[i*9+1]=niy; nuvF[i*9+2]=niz;
    nuvF[i*9+3]= ex*t1[0]+ey*t2[0]; nuvF[i*9+4]= ex*t1[1]+ey*t2[1]; nuvF[i*9+5]= ex*t1[2]+ey*t2[2];
    nuvF[i*9+6]=-ey*t1[0]+ex*t2[0]; nuvF[i*9+7]=-ey*t1[1]+ex*t2[1]; nuvF[i*9+8]=-ey*t1[2]+ex*t2[2];
  }
}

// ---- k5: conv via MFMA, i-as-M formulation (no LDS matmul operands) --------
// xi[i,h] = sum_c a2[h,c]*(G_c·H)[i,h] + b2[h]*(W·H)[i,h]
// A_c[m=i][k=j] = win*relu(r_c) computed in-register per lane (i=i0+c16,
// j=q*8+t).  B[k=j][n=h] = H[j][h] -> contiguous b128 load from hTb[h][j].
// D row=q*4+r -> i, col=c16 -> h (m89-verified). Per-block j-partial, k6a sums.
__global__ __launch_bounds__(256) void k5_conv(const float* __restrict__ pF,
                                               const float* __restrict__ nF,
                                               const float* __restrict__ nuvF,
                                               const unsigned short* __restrict__ hTb,
                                               const float* cv_a1, const float* cv_b1,
                                               const float* cv_a2, const float* cv_b2,
                                               float* __restrict__ xiP){
  __shared__ __align__(16) float vq[4][64][8];
  __shared__ float red[4][64][4];
  int lane = threadIdx.x & 63, w = threadIdx.x >> 6;
  int c16 = lane & 15, q = lane >> 4;
  int it = blockIdx.x >> 2, jseg = blockIdx.x & (JSPL-1);
  int i0 = it*16;
  int i = i0 + c16;                       // this lane's A row
  float pix=pF[i*3+0], piy=pF[i*3+1], piz=pF[i*3+2];
  float nu[9];
#pragma unroll
  for(int k=0;k<9;k++) nu[k]=nuvF[i*9+k];
  float a1w[8][3], b1w[8];
#pragma unroll
  for(int c=0;c<8;c++){
    a1w[c][0]=cv_a1[c*3+0]; a1w[c][1]=cv_a1[c*3+1]; a1w[c][2]=cv_a1[c*3+2];
    b1w[c]=cv_b1[c];
  }
  f32x4v acc[9];
#pragma unroll
  for(int c=0;c<9;c++) acc[c]=(f32x4v){0.0f,0.0f,0.0f,0.0f};

  int jbeg = jseg*(NPTS/JSPL) + w*(NPTS/JSPL/4);
  int jend = jbeg + (NPTS/JSPL/4);
#pragma unroll 1
  for(int jb=jbeg; jb<jend; jb+=64){
    int j = jb + lane;
    // cooperative stage of p/n for 64 j
    *(float4*)&vq[w][lane][0] = make_float4(pF[j*3+0],pF[j*3+1],pF[j*3+2],0.0f);
    *(float4*)&vq[w][lane][4] = make_float4(nF[j*3+0],nF[j*3+1],nF[j*3+2],0.0f);
    wave_lds_fence();
#pragma unroll
    for(int q2=0;q2<2;q2++){
      int jb2 = jb + q2*32;
      bf16x8v bfr = *(const bf16x8v*)(hTb + c16*NPTS + jb2 + q*8);
      bf16x8v af[9];
#pragma unroll
      for(int t=0;t<8;t++){
        int rloc = q2*32 + q*8 + t;
        float4 P  = *(const float4*)&vq[w][rloc][0];
        float4 Nj = *(const float4*)&vq[w][rloc][4];
        float dx=P.x-pix, dy=P.y-piy, dz=P.z-piz;
        float d2=dx*dx+dy*dy+dz*dz;
        float f=2.0f-(Nj.x*nu[0]+Nj.y*nu[1]+Nj.z*nu[2]);
        float win=exp2f(-d2*f*f*LOG2E);
        float X0=nu[0]*dx+nu[1]*dy+nu[2]*dz;
        float X1=nu[3]*dx+nu[4]*dy+nu[5]*dz;
        float X2=nu[6]*dx+nu[7]*dy+nu[8]*dz;
#pragma unroll
        for(int c=0;c<8;c++){
          float r=fmaf(X0,a1w[c][0],fmaf(X1,a1w[c][1],fmaf(X2,a1w[c][2],b1w[c])));
          af[c][t]=__builtin_bit_cast(__bf16, f2bf(win*fmaxf(r,0.0f)));
        }
        af[8][t]=__builtin_bit_cast(__bf16, f2bf(win));
      }
#pragma unroll
      for(int c=0;c<9;c++)
        acc[c] = __builtin_amdgcn_mfma_f32_16x16x32_bf16(af[c], bfr, acc[c], 0,0,0);
    }
    wave_lds_fence();
  }
  // epilogue: lane holds D[i0+q*4+r][h=c16]; apply a2/b2, combine 4 waves
  float a2row[8];
#pragma unroll
  for(int c=0;c<8;c++) a2row[c]=cv_a2[c16*8+c];
  float b2v = cv_b2[c16];
#pragma unroll
  for(int r=0;r<4;r++){
    float xi = acc[8][r]*b2v;
#pragma unroll
    for(int c=0;c<8;c++) xi += acc[c][r]*a2row[c];
    red[w][lane][r]=xi;
  }
  __syncthreads();
  if(w==0){
#pragma unroll
    for(int r=0;r<4;r++){
      float v = red[0][lane][r]+red[1][lane][r]+red[2][lane][r]+red[3][lane][r];
      xiP[((size_t)jseg*NPTS + (i0 + q*4 + r))*16 + c16] = v;
    }
  }
}

// ---- k6a: sum xiP slices + no-MLP + GN-out stats ---------------------------
__global__ __launch_bounds__(256) void k6a(const float* __restrict__ xiP,
    const float* no_w1, const float* no_b1, const float* no_w2, const float* no_b2,
    float* __restrict__ tF, float* __restrict__ stats2){
  int i = blockIdx.x*256 + threadIdx.x;
  int lane = threadIdx.x & 63;
  float xi[16];
#pragma unroll
  for(int k=0;k<16;k++){
    float v=0.0f;
#pragma unroll
    for(int s=0;s<JSPL;s++) v += xiP[((size_t)s*NPTS + i)*16 + k];
    xi[k]=v;
  }
  float t1[16];
#pragma unroll
  for(int o=0;o<16;o++){
    float t=ldb(no_b1,o);
#pragma unroll
    for(int k=0;k<16;k++) t += xi[k]*ldb(no_w1,o*16+k);
    t1[o]=lk(t);
  }
  float t2[16];
#pragma unroll
  for(int o=0;o<16;o++){
    float t=ldb(no_b2,o);
#pragma unroll
    for(int k=0;k<16;k++) t += t1[k]*ldb(no_w2,o*16+k);
    t2[o]=lk(t);
    tF[i*16+o]=t2[o];
  }
  float gs[4]={0,0,0,0}, gq[4]={0,0,0,0};
#pragma unroll
  for(int c=0;c<16;c++){ gs[c>>2]+=t2[c]; gq[c>>2]+=t2[c]*t2[c]; }
  __shared__ float ls[8];
  if(threadIdx.x<8) ls[threadIdx.x]=0.0f;
  __syncthreads();
#pragma unroll
  for(int g=0;g<4;g++){ gs[g]=wsum64(gs[g]); gq[g]=wsum64(gq[g]); }
  if(lane==0){
#pragma unroll
    for(int g=0;g<4;g++){ atomicAdd(&ls[2*g],gs[g]); atomicAdd(&ls[2*g+1],gq[g]); }
  }
  __syncthreads();
  if(threadIdx.x<8) atomicAdd(&stats2[threadIdx.x], ls[threadIdx.x]);
}

// ---- k6c ----
__global__ __launch_bounds__(256) void k6c(const float* __restrict__ tF,
    const float* __restrict__ xfF, const float* __restrict__ stats2,
    const float* gw, const float* gb,
    const float* ll_w1, const float* ll_b1, const float* ll_w2, const float* ll_b2,
    const float* lt_w, const float* lt_b,
    float* __restrict__ out){
  int i = blockIdx.x*256 + threadIdx.x;
  float m[4], r[4];
#pragma unroll
  for(int g=0;g<4;g++){
    float mean = stats2[2*g]*(1.0f/(4.0f*NPTS));
    float var  = stats2[2*g+1]*(1.0f/(4.0f*NPTS)) - mean*mean;
    m[g]=mean; r[g]=1.0f/sqrtf(var+1e-5f);
  }
  float tn[16];
#pragma unroll
  for(int c=0;c<16;c++){
    int g=c>>2;
    tn[c]=(tF[i*16+c]-m[g])*r[g]*ldb(gw,c)+ldb(gb,c);
  }
  float z1[16];
#pragma unroll
  for(int o=0;o<16;o++){
    float t=ldb(ll_b1,o);
#pragma unroll
    for(int k=0;k<16;k++) t += tn[k]*ldb(ll_w1,o*16+k);
    z1[o]=fmaxf(t,0.0f);
  }
  float xf[DINF];
#pragma unroll
  for(int k=0;k<DINF;k++) xf[k]=xfF[i*DINF+k];
#pragma unroll
  for(int o=0;o<16;o++){
    float z=ldb(ll_b2,o);
#pragma unroll
    for(int k=0;k<16;k++) z += z1[k]*ldb(ll_w2,o*16+k);
    float lt=ldb(lt_b,o);
#pragma unroll
    for(int k=0;k<DINF;k++) lt += xf[k]*ldb(lt_w,o*DINF+k);
    out[i*16+o]=z+lt;
  }
}

extern "C" void kernel_launch(void* const* d_in, const int* in_sizes, int n_in,
                              void* d_out, int out_size, void* d_ws, size_t ws_size,
                              hipStream_t stream){
  const float* verts    = (const float*)d_in[0];
  const float* vnormals = (const float*)d_in[1];
  const float* x        = (const float*)d_in[2];
  const float* os_w1    = (const float*)d_in[3];
  const float* os_b1    = (const float*)d_in[4];
  const float* os_w2    = (const float*)d_in[5];
  const float* os_b2    = (const float*)d_in[6];
  const float* ni_w1    = (const float*)d_in[7];
  const float* ni_b1    = (const float*)d_in[8];
  const float* ni_w2    = (const float*)d_in[9];
  const float* ni_b2    = (const float*)d_in[10];
  const float* gn_in_w  = (const float*)d_in[11];
  const float* gn_in_b  = (const float*)d_in[12];
  const float* cv_a1    = (const float*)d_in[13];
  const float* cv_b1    = (const float*)d_in[14];
  const float* cv_a2    = (const float*)d_in[15];
  const float* cv_b2    = (const float*)d_in[16];
  const float* no_w1    = (const float*)d_in[17];
  const float* no_b1    = (const float*)d_in[18];
  const float* no_w2    = (const float*)d_in[19];
  const float* no_b2    = (const float*)d_in[20];
  const float* gn_out_w = (const float*)d_in[21];
  const float* gn_out_b = (const float*)d_in[22];
  const float* ll_w1    = (const float*)d_in[23];
  const float* ll_b1    = (const float*)d_in[24];
  const float* ll_w2    = (const float*)d_in[25];
  const float* ll_b2    = (const float*)d_in[26];
  const float* lt_w     = (const float*)d_in[27];
  const float* lt_b     = (const float*)d_in[28];

  float* W = (float*)d_ws;
  size_t off = 0;
  float* vertsF = W + off; off += (size_t)3*NPTS;
  float* nF     = W + off; off += (size_t)3*NPTS;
  float* pF     = W + off; off += (size_t)3*NPTS;
  float* xfF    = W + off; off += (size_t)DINF*NPTS;
  float* sc     = W + off; off += (size_t)13*NPTS*5;
  float* wOS    = W + off; off += (size_t)NPTS;
  float* hPre   = W + off; off += (size_t)16*NPTS;
  unsigned short* hTb = (unsigned short*)(W + off); off += (size_t)8*NPTS;
  float* nuvF   = W + off; off += (size_t)9*NPTS;
  float* xiP    = W + off; off += (size_t)JSPL*16*NPTS;
  float* tF     = W + off; off += (size_t)16*NPTS;
  float* stats  = W + off; off += 16;
  float* mom2 = hPre;   // aliased: dead until k3 writes hPre; k2s done before k3

  hipMemsetAsync(stats, 0, 16*sizeof(float), stream);
  hipMemsetAsync(sc,   0, (size_t)13*NPTS*5*sizeof(float), stream);
  hipMemsetAsync(mom2, 0, (size_t)12*NPTS*5*sizeof(float), stream);

  k0_convert<<<NPTS/256, 256, 0, stream>>>(verts, vnormals, x, vertsF, nF, pF, xfF);
  k1m<<<NPTS/8, 512, 0, stream>>>(vertsF, nF, sc);
  k2m<<<NPTS/8, 512, 0, stream>>>(vertsF, sc, mom2);
  k2s<<<5*NPTS/256, 256, 0, stream>>>(vertsF, sc, mom2, xfF);
  k3_mlps<<<NPTS/256, 256, 0, stream>>>(xfF, os_w1, os_b1, os_w2, os_b2,
                                        ni_w1, ni_b1, ni_w2, ni_b2, wOS, hPre, stats);
  k3c_gn<<<NPTS/256, 256, 0, stream>>>(hPre, stats, gn_in_w, gn_in_b, hTb);
  k4_ov<<<NPTS/2, 256, 0, stream>>>(pF, nF, wOS, nuvF);
  k5_conv<<<(NPTS/16)*JSPL, 256, 0, stream>>>(pF, nF, nuvF, hTb,
                                              cv_a1, cv_b1, cv_a2, cv_b2, xiP);
  k6a<<<NPTS/256, 256, 0, stream>>>(xiP, no_w1, no_b1, no_w2, no_b2, tF, stats+8);
  k6c<<<NPTS/256, 256, 0, stream>>>(tF, xfF, stats+8, gn_out_w, gn_out_b,
                                    ll_w1, ll_b1, ll_w2, ll_b2, lt_w, lt_b, (float*)d_out);
}